// Round 2
// baseline (799.584 us; speedup 1.0000x reference)
//
#include <hip/hip_runtime.h>
#include <stdint.h>

typedef short  short8  __attribute__((ext_vector_type(8)));
typedef unsigned short ushort8 __attribute__((ext_vector_type(8)));
typedef float  f32x4   __attribute__((ext_vector_type(4)));

#define BB  4
#define SQL 2048
#define SKL 2048
#define NEGV -1e9f

__device__ __forceinline__ unsigned short f2bf(float f){
  union { float f; uint32_t u; } x; x.f = f;
  return (unsigned short)((x.u + 0x7FFFu + ((x.u >> 16) & 1u)) >> 16);
}
__device__ __forceinline__ float bf2f(unsigned short h){
  union { uint32_t u; float f; } x; x.u = ((uint32_t)h) << 16;
  return x.f;
}

// ---------------- mask dtype sniffing ----------------
// Reads only the first elems/4 bytes (safe for every candidate dtype).
// cnt[0]: nonzero bytes at i%4!=0  (u8-bool -> ~1.2M, int32 0/1 -> 0)
// cnt[1]: bytes>1                  (u8/int32 -> 0, bf16/f32-coded -> big)
// cnt[2]: nonzero bytes at i%4==1  (bf16-coded -> ~400K, f32-coded -> 0)
__global__ void mask_detect(const uint8_t* __restrict__ m, int* __restrict__ cnt){
  const long n4 = (long)BB * SQL * SKL / 4;
  long idx  = (long)blockIdx.x * blockDim.x + threadIdx.x;
  long step = (long)gridDim.x * blockDim.x;
  int c0 = 0, c1 = 0, c2 = 0;
  for (long i4 = idx; i4 < n4; i4 += step){
    uchar4 b = ((const uchar4*)m)[i4];
    c0 += (b.y != 0) + (b.z != 0) + (b.w != 0);
    c1 += (b.x > 1) + (b.y > 1) + (b.z > 1) + (b.w > 1);
    c2 += (b.y != 0);
  }
  #pragma unroll
  for (int o = 32; o >= 1; o >>= 1){
    c0 += __shfl_xor(c0, o); c1 += __shfl_xor(c1, o); c2 += __shfl_xor(c2, o);
  }
  if ((threadIdx.x & 63) == 0){
    atomicAdd(&cnt[0], c0); atomicAdd(&cnt[1], c1); atomicAdd(&cnt[2], c2);
  }
}

// ---------------- NT GEMM: C[m,n] = sum_k A[m,k] * B[n,k] ----------------
// m97 structure: 128x128 tile, BK=32, 4 waves, 16x16x32 bf16 MFMA.
// AMODE/BMODE: 0 = operand is bf16, stage via global_load_lds (16B);
//              1 = operand is f32, reg-stage (float4 x2 -> cvt -> ds_write_b128).
// EPI: 0 = store bf16 C; 1 = scale+mask -> bf16 scores (mask decoded via cnt);
//      2 = store f32 C.
template<int AMODE, int BMODE, int EPI>
__global__ __launch_bounds__(256, 2)
void gemm_nt(const void* __restrict__ Abv, const void* __restrict__ Bbv,
             void* __restrict__ Cb, const void* __restrict__ mask,
             const int* __restrict__ cnt,
             long Abs, long Bbs, long Cbs, float scale)
{
  constexpr int K = 2048, LD = 2048;
  const int bz = blockIdx.z;
  const int tid = threadIdx.x, lane = tid & 63, wave = tid >> 6;
  const int wr = wave >> 1, wc = wave & 1;
  const long tm = (long)blockIdx.y * 128, tn = (long)blockIdx.x * 128;
  __shared__ unsigned short lA[128 * 32];
  __shared__ unsigned short lB[128 * 32];
  f32x4 acc[4][4] = {};

  // 512 chunks of 8 elems per 128x32 tile; thread handles chunks tid, tid+256.
  // chunk c: row = c>>2 (0..127), q = (c&3)*8 (0..24); LDS ushort idx = c*8 = row*32+q.
  const int c0 = tid, c1 = tid + 256;
  const int r0 = c0 >> 2, q0 = (c0 & 3) * 8;
  const int r1 = c1 >> 2, q1 = (c1 & 3) * 8;

  const unsigned short* A16 = (const unsigned short*)Abv + (long)bz * Abs;
  const unsigned short* B16 = (const unsigned short*)Bbv + (long)bz * Bbs;
  const float*          A32 = (const float*)Abv + (long)bz * Abs;
  const float*          B32 = (const float*)Bbv + (long)bz * Bbs;

  for (int k0 = 0; k0 < K; k0 += 32){
    if (AMODE == 0){
      __builtin_amdgcn_global_load_lds((const __attribute__((address_space(1))) void*)(A16 + (tm + r0) * LD + q0 + k0),
                                       (__attribute__((address_space(3))) void*)(lA + c0 * 8), 16, 0, 0);
      __builtin_amdgcn_global_load_lds((const __attribute__((address_space(1))) void*)(A16 + (tm + r1) * LD + q1 + k0),
                                       (__attribute__((address_space(3))) void*)(lA + c1 * 8), 16, 0, 0);
    } else {
      f32x4 u0 = *(const f32x4*)(A32 + (tm + r0) * LD + q0 + k0);
      f32x4 u1 = *(const f32x4*)(A32 + (tm + r0) * LD + q0 + k0 + 4);
      f32x4 u2 = *(const f32x4*)(A32 + (tm + r1) * LD + q1 + k0);
      f32x4 u3 = *(const f32x4*)(A32 + (tm + r1) * LD + q1 + k0 + 4);
      ushort8 w0, w1;
      #pragma unroll
      for (int j = 0; j < 4; ++j){
        w0[j] = f2bf(u0[j]); w0[j + 4] = f2bf(u1[j]);
        w1[j] = f2bf(u2[j]); w1[j + 4] = f2bf(u3[j]);
      }
      *(ushort8*)(lA + c0 * 8) = w0;
      *(ushort8*)(lA + c1 * 8) = w1;
    }
    if (BMODE == 0){
      __builtin_amdgcn_global_load_lds((const __attribute__((address_space(1))) void*)(B16 + (tn + r0) * LD + q0 + k0),
                                       (__attribute__((address_space(3))) void*)(lB + c0 * 8), 16, 0, 0);
      __builtin_amdgcn_global_load_lds((const __attribute__((address_space(1))) void*)(B16 + (tn + r1) * LD + q1 + k0),
                                       (__attribute__((address_space(3))) void*)(lB + c1 * 8), 16, 0, 0);
    } else {
      f32x4 u0 = *(const f32x4*)(B32 + (tn + r0) * LD + q0 + k0);
      f32x4 u1 = *(const f32x4*)(B32 + (tn + r0) * LD + q0 + k0 + 4);
      f32x4 u2 = *(const f32x4*)(B32 + (tn + r1) * LD + q1 + k0);
      f32x4 u3 = *(const f32x4*)(B32 + (tn + r1) * LD + q1 + k0 + 4);
      ushort8 w0, w1;
      #pragma unroll
      for (int j = 0; j < 4; ++j){
        w0[j] = f2bf(u0[j]); w0[j + 4] = f2bf(u1[j]);
        w1[j] = f2bf(u2[j]); w1[j + 4] = f2bf(u3[j]);
      }
      *(ushort8*)(lB + c0 * 8) = w0;
      *(ushort8*)(lB + c1 * 8) = w1;
    }
    __syncthreads();

    short8 aF[4], bF[4];
    #pragma unroll
    for (int m = 0; m < 4; ++m)
      aF[m] = *(const short8*)(lA + (wr * 64 + m * 16 + (lane & 15)) * 32 + (lane >> 4) * 8);
    #pragma unroll
    for (int n = 0; n < 4; ++n)
      bF[n] = *(const short8*)(lB + (wc * 64 + n * 16 + (lane & 15)) * 32 + (lane >> 4) * 8);

    #pragma unroll
    for (int m = 0; m < 4; ++m)
      #pragma unroll
      for (int n = 0; n < 4; ++n)
        acc[m][n] = __builtin_amdgcn_mfma_f32_16x16x32_bf16(aF[m], bF[n], acc[m][n], 0, 0, 0);
    __syncthreads();
  }

  // C/D layout (m89-verified): col = lane&15, row = (lane>>4)*4 + j
  const int colo = lane & 15, rowg = (lane >> 4) * 4;
  if (EPI == 0){
    unsigned short* C = (unsigned short*)Cb + (long)bz * Cbs;
    #pragma unroll
    for (int m = 0; m < 4; ++m)
      #pragma unroll
      for (int j = 0; j < 4; ++j){
        const long row = tm + wr * 64 + m * 16 + rowg + j;
        unsigned short* cr = C + row * LD + tn + wc * 64 + colo;
        #pragma unroll
        for (int n = 0; n < 4; ++n) cr[n * 16] = f2bf(acc[m][n][j]);
      }
  } else if (EPI == 2){
    float* C = (float*)Cb + (long)bz * Cbs;
    #pragma unroll
    for (int m = 0; m < 4; ++m)
      #pragma unroll
      for (int j = 0; j < 4; ++j){
        const long row = tm + wr * 64 + m * 16 + rowg + j;
        float* cr = C + row * LD + tn + wc * 64 + colo;
        #pragma unroll
        for (int n = 0; n < 4; ++n) cr[n * 16] = acc[m][n][j];
      }
  } else {
    const int a0 = cnt[0], a1 = cnt[1], a2 = cnt[2];
    // 0: uint8 bool, 1: int32, 2: bf16-coded, 3: f32-coded
    const int mmode = (a1 == 0) ? (a0 > 1000 ? 0 : 1) : (a2 > 1000 ? 2 : 3);
    unsigned short* C = (unsigned short*)Cb + (long)bz * Cbs;
    const long mbase = (long)bz * SQL * SKL;
    #pragma unroll
    for (int m = 0; m < 4; ++m)
      #pragma unroll
      for (int j = 0; j < 4; ++j){
        const long row = tm + wr * 64 + m * 16 + rowg + j;
        #pragma unroll
        for (int n = 0; n < 4; ++n){
          const long col = tn + wc * 64 + n * 16 + colo;
          const long midx = mbase + row * SKL + col;
          bool msk;
          if (mmode == 0)      msk = ((const uint8_t*)mask)[midx] != 0;
          else if (mmode == 1) msk = ((const int*)mask)[midx] != 0;
          else if (mmode == 2) msk = ((const unsigned short*)mask)[midx] != 0;
          else                 msk = ((const uint32_t*)mask)[midx] != 0;
          float vv = acc[m][n][j] * scale;
          if (msk) vv = NEGV;
          C[row * SKL + col] = f2bf(vv);
        }
      }
  }
}

// ---------------- row softmax: S bf16 [row,0..2047] -> P bf16 ----------------
__global__ __launch_bounds__(256, 4)
void softmax_rows(const unsigned short* __restrict__ S, unsigned short* __restrict__ P){
  const long row = blockIdx.x;
  const int t = threadIdx.x;
  ushort8 u = *((const ushort8*)(S + row * SKL) + t);
  float v[8];
  #pragma unroll
  for (int j = 0; j < 8; ++j) v[j] = bf2f(u[j]);
  float mx = v[0];
  #pragma unroll
  for (int j = 1; j < 8; ++j) mx = fmaxf(mx, v[j]);
  #pragma unroll
  for (int o = 32; o >= 1; o >>= 1) mx = fmaxf(mx, __shfl_xor(mx, o));
  __shared__ float red[8];
  const int wv = t >> 6, ln = t & 63;
  if (ln == 0) red[wv] = mx;
  __syncthreads();
  mx = fmaxf(fmaxf(red[0], red[1]), fmaxf(red[2], red[3]));
  float e[8], sum = 0.f;
  #pragma unroll
  for (int j = 0; j < 8; ++j){ e[j] = exp2f((v[j] - mx) * 1.4426950408889634f); sum += e[j]; }
  #pragma unroll
  for (int o = 32; o >= 1; o >>= 1) sum += __shfl_xor(sum, o);
  if (ln == 0) red[4 + wv] = sum;
  __syncthreads();
  sum = red[4] + red[5] + red[6] + red[7];
  const float inv = 1.0f / sum;
  ushort8 o8;
  #pragma unroll
  for (int j = 0; j < 8; ++j) o8[j] = f2bf(e[j] * inv);
  *((ushort8*)(P + row * SKL) + t) = o8;
}

// ---------------- host ----------------
extern "C" void kernel_launch(void* const* d_in, const int* in_sizes, int n_in,
                              void* d_out, int out_size, void* d_ws, size_t ws_size,
                              hipStream_t stream)
{
  (void)in_sizes; (void)n_in; (void)out_size;
  const void* x    = d_in[0];   // f32 [B,SKV,D]
  const void* encq = d_in[1];   // f32 [B,SQ,D]
  const void* enck = d_in[2];   // f32 [B,SKV,D]
  const void* imsk = d_in[3];   // bool-ish [B,SQ,SKV] (sniffed)
  const void* Wq   = d_in[4];   // f32 [D,D]
  const void* Wk   = d_in[5];
  const void* Wv   = d_in[6];

  uint8_t* ws = (uint8_t*)d_ws;
  int* cnt = (int*)ws;                                   // 4 KiB
  unsigned short* Q  = (unsigned short*)(ws + 4096);     // 32 MiB bf16
  unsigned short* Kp = Q  + 16777216;
  unsigned short* Vt = Kp + 16777216;
  unsigned short* P  = Q;                                // alias: Q dead after S
  unsigned short* S;
  const size_t need = 4096 + 4ull * 33554432;
  if (ws_size >= need) S = Vt + 16777216;
  else                 S = (unsigned short*)d_out;       // 33.5MB inside 67MB f32 out

  hipMemsetAsync(cnt, 0, 4096, stream);
  mask_detect<<<256, 256, 0, stream>>>((const uint8_t*)imsk, cnt);

  dim3 blk(256), grd(16, 16, BB);
  const long NN = (long)2048 * 2048;
  const float scale = 0.022097086912079608f;  // 1/sqrt(2048)

  // Q = enc_q @ Wq^T ; K' = enc_k @ Wk^T ; V^T = Wv @ x^T (all NT, f32 in, bf16 out)
  gemm_nt<1,1,0><<<grd, blk, 0, stream>>>(encq, Wq, Q,  nullptr, cnt, NN, 0, NN, 1.f);
  gemm_nt<1,1,0><<<grd, blk, 0, stream>>>(enck, Wk, Kp, nullptr, cnt, NN, 0, NN, 1.f);
  gemm_nt<1,1,0><<<grd, blk, 0, stream>>>(Wv,   x,  Vt, nullptr, cnt, 0, NN, NN, 1.f);
  // S = mask(scale * Q K'^T)  -> bf16
  gemm_nt<0,0,1><<<grd, blk, 0, stream>>>(Q, Kp, S, imsk, cnt, NN, NN, NN, scale);
  softmax_rows<<<BB * SQL, 256, 0, stream>>>(S, P);
  // O = P V^T^T  -> f32 d_out
  gemm_nt<0,0,2><<<grd, blk, 0, stream>>>(P, Vt, d_out, nullptr, cnt, NN, NN, NN, 1.f);
}

// Round 3
// 728.238 us; speedup vs baseline: 1.0980x; 1.0980x over previous
//
#include <hip/hip_runtime.h>
#include <stdint.h>

typedef short  short8  __attribute__((ext_vector_type(8)));
typedef unsigned short ushort8 __attribute__((ext_vector_type(8)));
typedef float  f32x4   __attribute__((ext_vector_type(4)));

#define BB  4
#define SQL 2048
#define SKL 2048
#define NEGV -1e9f
#define AS1 __attribute__((address_space(1)))
#define AS3 __attribute__((address_space(3)))

__device__ __forceinline__ unsigned short f2bf(float f){
  union { float f; uint32_t u; } x; x.f = f;
  return (unsigned short)((x.u + 0x7FFFu + ((x.u >> 16) & 1u)) >> 16);
}
__device__ __forceinline__ float bf2f(unsigned short h){
  union { uint32_t u; float f; } x; x.u = ((uint32_t)h) << 16;
  return x.f;
}

// ---------------- mask dtype sniffing ----------------
__global__ void mask_detect(const uint8_t* __restrict__ m, int* __restrict__ cnt){
  const long n4 = (long)BB * SQL * SKL / 4;
  long idx  = (long)blockIdx.x * blockDim.x + threadIdx.x;
  long step = (long)gridDim.x * blockDim.x;
  int c0 = 0, c1 = 0, c2 = 0;
  for (long i4 = idx; i4 < n4; i4 += step){
    uchar4 b = ((const uchar4*)m)[i4];
    c0 += (b.y != 0) + (b.z != 0) + (b.w != 0);
    c1 += (b.x > 1) + (b.y > 1) + (b.z > 1) + (b.w > 1);
    c2 += (b.y != 0);
  }
  #pragma unroll
  for (int o = 32; o >= 1; o >>= 1){
    c0 += __shfl_xor(c0, o); c1 += __shfl_xor(c1, o); c2 += __shfl_xor(c2, o);
  }
  if ((threadIdx.x & 63) == 0){
    atomicAdd(&cnt[0], c0); atomicAdd(&cnt[1], c1); atomicAdd(&cnt[2], c2);
  }
}

// ---------------- NT GEMM body: C[m,n] = sum_k A[m,k]*B[n,k] ----------------
// 128x128 tile, BK=32, 4 waves, 16x16x32 bf16 MFMA, f32 accumulate.
// Double-buffered LDS, ONE barrier per K-step (T3-minimum recipe):
//   issue STAGE(t+1) -> ds_read/MFMA(t) -> [reg-path: cvt+ds_write(t+1)] -> barrier.
// AMODE/BMODE: 0 = bf16 operand via global_load_lds(16B); 1 = f32 operand via
// reg-stage (issue-early / write-late, T14).
// EPI: 0 = bf16 C; 1 = scale+mask -> bf16 scores; 2 = f32 C.
template<int AMODE, int BMODE, int EPI>
__device__ __forceinline__ void gemm_body(
    const void* __restrict__ Av, const void* __restrict__ Bv,
    void* __restrict__ Cb, const void* __restrict__ mask, const int* __restrict__ cnt,
    int bz, long Abs, long Bbs, long Cbs, long tm, long tn, float scale,
    unsigned short (*lA)[4096], unsigned short (*lB)[4096])
{
  constexpr int K = 2048, LD = 2048;
  const int tid = threadIdx.x, lane = tid & 63, wave = tid >> 6;
  const int wr = wave >> 1, wc = wave & 1;
  const int c0 = tid, c1 = tid + 256;
  const int r0 = c0 >> 2, q0 = (c0 & 3) * 8;
  const int r1 = c1 >> 2, q1 = (c1 & 3) * 8;

  const unsigned short* A16 = (const unsigned short*)Av + (long)bz * Abs;
  const unsigned short* B16 = (const unsigned short*)Bv + (long)bz * Bbs;
  const float*          A32 = (const float*)Av + (long)bz * Abs;
  const float*          B32 = (const float*)Bv + (long)bz * Bbs;

  f32x4 acc[4][4] = {};
  f32x4 sA[4], sB[4];   // reg-staging (MODE==1)

  auto issueA = [&](int buf, int kk){
    if constexpr (AMODE == 0){
      __builtin_amdgcn_global_load_lds((const AS1 void*)(A16 + (tm + r0) * LD + q0 + kk),
                                       (AS3 void*)(lA[buf] + c0 * 8), 16, 0, 0);
      __builtin_amdgcn_global_load_lds((const AS1 void*)(A16 + (tm + r1) * LD + q1 + kk),
                                       (AS3 void*)(lA[buf] + c1 * 8), 16, 0, 0);
    } else {
      sA[0] = *(const f32x4*)(A32 + (tm + r0) * LD + q0 + kk);
      sA[1] = *(const f32x4*)(A32 + (tm + r0) * LD + q0 + kk + 4);
      sA[2] = *(const f32x4*)(A32 + (tm + r1) * LD + q1 + kk);
      sA[3] = *(const f32x4*)(A32 + (tm + r1) * LD + q1 + kk + 4);
    }
  };
  auto issueB = [&](int buf, int kk){
    if constexpr (BMODE == 0){
      __builtin_amdgcn_global_load_lds((const AS1 void*)(B16 + (tn + r0) * LD + q0 + kk),
                                       (AS3 void*)(lB[buf] + c0 * 8), 16, 0, 0);
      __builtin_amdgcn_global_load_lds((const AS1 void*)(B16 + (tn + r1) * LD + q1 + kk),
                                       (AS3 void*)(lB[buf] + c1 * 8), 16, 0, 0);
    } else {
      sB[0] = *(const f32x4*)(B32 + (tn + r0) * LD + q0 + kk);
      sB[1] = *(const f32x4*)(B32 + (tn + r0) * LD + q0 + kk + 4);
      sB[2] = *(const f32x4*)(B32 + (tn + r1) * LD + q1 + kk);
      sB[3] = *(const f32x4*)(B32 + (tn + r1) * LD + q1 + kk + 4);
    }
  };
  auto writeA = [&](int buf){
    if constexpr (AMODE == 1){
      ushort8 w0, w1;
      #pragma unroll
      for (int j = 0; j < 4; ++j){
        w0[j] = f2bf(sA[0][j]); w0[j + 4] = f2bf(sA[1][j]);
        w1[j] = f2bf(sA[2][j]); w1[j + 4] = f2bf(sA[3][j]);
      }
      *(ushort8*)(lA[buf] + c0 * 8) = w0;
      *(ushort8*)(lA[buf] + c1 * 8) = w1;
    }
  };
  auto writeB = [&](int buf){
    if constexpr (BMODE == 1){
      ushort8 w0, w1;
      #pragma unroll
      for (int j = 0; j < 4; ++j){
        w0[j] = f2bf(sB[0][j]); w0[j + 4] = f2bf(sB[1][j]);
        w1[j] = f2bf(sB[2][j]); w1[j + 4] = f2bf(sB[3][j]);
      }
      *(ushort8*)(lB[buf] + c0 * 8) = w0;
      *(ushort8*)(lB[buf] + c1 * 8) = w1;
    }
  };
  auto computeTile = [&](int buf){
    short8 aF[4], bF[4];
    #pragma unroll
    for (int m = 0; m < 4; ++m)
      aF[m] = *(const short8*)(lA[buf] + (wr * 64 + m * 16 + (lane & 15)) * 32 + (lane >> 4) * 8);
    #pragma unroll
    for (int n = 0; n < 4; ++n)
      bF[n] = *(const short8*)(lB[buf] + (wc * 64 + n * 16 + (lane & 15)) * 32 + (lane >> 4) * 8);
    #pragma unroll
    for (int m = 0; m < 4; ++m)
      #pragma unroll
      for (int n = 0; n < 4; ++n)
        acc[m][n] = __builtin_amdgcn_mfma_f32_16x16x32_bf16(aF[m], bF[n], acc[m][n], 0, 0, 0);
  };

  // prologue: stage tile 0 into buf 0
  issueA(0, 0); issueB(0, 0); writeA(0); writeB(0);
  __syncthreads();
  int cur = 0;
  for (int k0 = 0; k0 < K - 32; k0 += 32){
    issueA(cur ^ 1, k0 + 32);
    issueB(cur ^ 1, k0 + 32);
    computeTile(cur);
    writeA(cur ^ 1); writeB(cur ^ 1);
    __syncthreads();          // drains vmcnt(0): prefetched loads had full MFMA phase
    cur ^= 1;
  }
  computeTile(cur);           // last tile, no prefetch

  // C/D layout (m89-verified): col = lane&15, row = (lane>>4)*4 + j
  const int colo = lane & 15, rowg = (lane >> 4) * 4;
  if constexpr (EPI == 0){
    unsigned short* C = (unsigned short*)Cb + (long)bz * Cbs;
    #pragma unroll
    for (int m = 0; m < 4; ++m)
      #pragma unroll
      for (int j = 0; j < 4; ++j){
        const long row = tm + wr * 64 + m * 16 + rowg + j;
        unsigned short* cr = C + row * LD + tn + wc * 64 + colo;
        #pragma unroll
        for (int n = 0; n < 4; ++n) cr[n * 16] = f2bf(acc[m][n][j]);
      }
  } else if constexpr (EPI == 2){
    float* C = (float*)Cb + (long)bz * Cbs;
    #pragma unroll
    for (int m = 0; m < 4; ++m)
      #pragma unroll
      for (int j = 0; j < 4; ++j){
        const long row = tm + wr * 64 + m * 16 + rowg + j;
        float* cr = C + row * LD + tn + wc * 64 + colo;
        #pragma unroll
        for (int n = 0; n < 4; ++n) cr[n * 16] = acc[m][n][j];
      }
  } else {
    const int a0 = cnt[0], a1 = cnt[1], a2 = cnt[2];
    // 0: uint8 bool, 1: int32, 2: bf16-coded, 3: f32-coded
    const int mmode = (a1 == 0) ? (a0 > 1000 ? 0 : 1) : (a2 > 1000 ? 2 : 3);
    unsigned short* C = (unsigned short*)Cb + (long)bz * Cbs;
    const long mbase = (long)bz * SQL * SKL;
    #pragma unroll
    for (int m = 0; m < 4; ++m)
      #pragma unroll
      for (int j = 0; j < 4; ++j){
        const long row = tm + wr * 64 + m * 16 + rowg + j;
        #pragma unroll
        for (int n = 0; n < 4; ++n){
          const long col = tn + wc * 64 + n * 16 + colo;
          const long midx = mbase + row * SKL + col;
          bool msk;
          if (mmode == 0)      msk = ((const uint8_t*)mask)[midx] != 0;
          else if (mmode == 1) msk = ((const int*)mask)[midx] != 0;
          else if (mmode == 2) msk = ((const unsigned short*)mask)[midx] != 0;
          else                 msk = ((const uint32_t*)mask)[midx] != 0;
          float vv = acc[m][n][j] * scale;
          if (msk) vv = NEGV;
          C[row * SKL + col] = f2bf(vv);
        }
      }
  }
}

// bijective XCD swizzle (nwg % 8 == 0 for all our grids)
__device__ __forceinline__ void xcd_decode(int& bx, int& by, int& bz){
  const int gx = gridDim.x, gy = gridDim.y;
  const int nwg = gx * gy * gridDim.z;
  const int lid = blockIdx.x + gx * (blockIdx.y + gy * blockIdx.z);
  const int sw  = (lid & 7) * (nwg >> 3) + (lid >> 3);
  bx = sw % gx;
  const int t = sw / gx;
  by = t % gy;
  bz = t / gy;
}

template<int AMODE, int BMODE, int EPI>
__global__ __launch_bounds__(256, 2)
void gemm_nt(const void* __restrict__ Abv, const void* __restrict__ Bbv,
             void* __restrict__ Cb, const void* __restrict__ mask,
             const int* __restrict__ cnt,
             long Abs, long Bbs, long Cbs, float scale)
{
  __shared__ unsigned short lA[2][4096];
  __shared__ unsigned short lB[2][4096];
  int bx, by, bz; xcd_decode(bx, by, bz);
  gemm_body<AMODE, BMODE, EPI>(Abv, Bbv, Cb, mask, cnt, bz, Abs, Bbs, Cbs,
                               (long)by * 128, (long)bx * 128, scale, lA, lB);
}

// all three f32 projections fused: z 0-3 -> Q, 4-7 -> K', 8-11 -> V^T
__global__ __launch_bounds__(256, 2)
void gemm_proj3(const void* A0, const void* A1, const void* A2,
                const void* B0, const void* B1, const void* B2,
                void* C0, void* C1, void* C2)
{
  __shared__ unsigned short lA[2][4096];
  __shared__ unsigned short lB[2][4096];
  int bx, by, bz; xcd_decode(bx, by, bz);
  const int sec = bz >> 2, b = bz & 3;
  const long NN = (long)SQL * 2048;
  const void* Av = sec == 0 ? A0 : sec == 1 ? A1 : A2;
  const void* Bv = sec == 0 ? B0 : sec == 1 ? B1 : B2;
  void*       Cv = sec == 0 ? C0 : sec == 1 ? C1 : C2;
  const long Abs = (sec == 2) ? 0 : NN;
  const long Bbs = (sec == 2) ? NN : 0;
  gemm_body<1, 1, 0>(Av, Bv, Cv, nullptr, nullptr, b, Abs, Bbs, NN,
                     (long)by * 128, (long)bx * 128, 1.f, lA, lB);
}

// ---------------- row softmax: S bf16 [row,0..2047] -> P bf16 ----------------
__global__ __launch_bounds__(256, 4)
void softmax_rows(const unsigned short* __restrict__ S, unsigned short* __restrict__ P){
  const long row = blockIdx.x;
  const int t = threadIdx.x;
  ushort8 u = *((const ushort8*)(S + row * SKL) + t);
  float v[8];
  #pragma unroll
  for (int j = 0; j < 8; ++j) v[j] = bf2f(u[j]);
  float mx = v[0];
  #pragma unroll
  for (int j = 1; j < 8; ++j) mx = fmaxf(mx, v[j]);
  #pragma unroll
  for (int o = 32; o >= 1; o >>= 1) mx = fmaxf(mx, __shfl_xor(mx, o));
  __shared__ float red[8];
  const int wv = t >> 6, ln = t & 63;
  if (ln == 0) red[wv] = mx;
  __syncthreads();
  mx = fmaxf(fmaxf(red[0], red[1]), fmaxf(red[2], red[3]));
  float e[8], sum = 0.f;
  #pragma unroll
  for (int j = 0; j < 8; ++j){ e[j] = exp2f((v[j] - mx) * 1.4426950408889634f); sum += e[j]; }
  #pragma unroll
  for (int o = 32; o >= 1; o >>= 1) sum += __shfl_xor(sum, o);
  if (ln == 0) red[4 + wv] = sum;
  __syncthreads();
  sum = red[4] + red[5] + red[6] + red[7];
  const float inv = 1.0f / sum;
  ushort8 o8;
  #pragma unroll
  for (int j = 0; j < 8; ++j) o8[j] = f2bf(e[j] * inv);
  *((ushort8*)(P + row * SKL) + t) = o8;
}

// ---------------- host ----------------
extern "C" void kernel_launch(void* const* d_in, const int* in_sizes, int n_in,
                              void* d_out, int out_size, void* d_ws, size_t ws_size,
                              hipStream_t stream)
{
  (void)in_sizes; (void)n_in; (void)out_size;
  const void* x    = d_in[0];   // f32 [B,SKV,D]
  const void* encq = d_in[1];   // f32 [B,SQ,D]
  const void* enck = d_in[2];   // f32 [B,SKV,D]
  const void* imsk = d_in[3];   // bool-ish [B,SQ,SKV] (sniffed)
  const void* Wq   = d_in[4];   // f32 [D,D]
  const void* Wk   = d_in[5];
  const void* Wv   = d_in[6];

  uint8_t* ws = (uint8_t*)d_ws;
  int* cnt = (int*)ws;                                   // 4 KiB
  unsigned short* Q  = (unsigned short*)(ws + 4096);     // 32 MiB bf16 each
  unsigned short* Kp = Q  + 16777216;
  unsigned short* Vt = Kp + 16777216;
  unsigned short* P  = Q;                                // alias: Q dead after S
  unsigned short* S;
  const size_t need = 4096 + 4ull * 33554432;
  if (ws_size >= need) S = Vt + 16777216;
  else                 S = (unsigned short*)d_out;       // fits in 67MB f32 out

  hipMemsetAsync(cnt, 0, 4096, stream);
  mask_detect<<<256, 256, 0, stream>>>((const uint8_t*)imsk, cnt);

  dim3 blk(256);
  const long NN = (long)2048 * 2048;
  const float scale = 0.022097086912079608f;  // 1/sqrt(2048)

  // Q = enc_q @ Wq^T ; K' = enc_k @ Wk^T ; V^T = Wv @ x^T   (one fused dispatch)
  gemm_proj3<<<dim3(16, 16, 12), blk, 0, stream>>>(encq, enck, Wv, Wq, Wk, x, Q, Kp, Vt);
  // S = mask(scale * Q K'^T) -> bf16
  gemm_nt<0, 0, 1><<<dim3(16, 16, BB), blk, 0, stream>>>(Q, Kp, S, imsk, cnt, NN, NN, NN, scale);
  softmax_rows<<<BB * SQL, 256, 0, stream>>>(S, P);
  // O = P @ (V^T)^T -> f32 d_out
  gemm_nt<0, 0, 2><<<dim3(16, 16, BB), blk, 0, stream>>>(P, Vt, d_out, nullptr, cnt, NN, NN, NN, 1.f);
}

// Round 4
// 573.473 us; speedup vs baseline: 1.3943x; 1.2699x over previous
//
#include <hip/hip_runtime.h>
#include <stdint.h>

typedef short  short8  __attribute__((ext_vector_type(8)));
typedef unsigned short ushort8 __attribute__((ext_vector_type(8)));
typedef float  f32x4   __attribute__((ext_vector_type(4)));

#define BB  4
#define SQL 2048
#define SKL 2048
#define NEGV -1e9f
#define AS1 __attribute__((address_space(1)))
#define AS3 __attribute__((address_space(3)))

__device__ __forceinline__ unsigned short f2bf(float f){
  union { float f; uint32_t u; } x; x.f = f;
  return (unsigned short)((x.u + 0x7FFFu + ((x.u >> 16) & 1u)) >> 16);
}
__device__ __forceinline__ float bf2f(unsigned short h){
  union { uint32_t u; float f; } x; x.u = ((uint32_t)h) << 16;
  return x.f;
}

// ---------------- mask dtype sniffing ----------------
__global__ void mask_detect(const uint8_t* __restrict__ m, int* __restrict__ cnt){
  const long n4 = (long)BB * SQL * SKL / 4;
  long idx  = (long)blockIdx.x * blockDim.x + threadIdx.x;
  long step = (long)gridDim.x * blockDim.x;
  int c0 = 0, c1 = 0, c2 = 0;
  for (long i4 = idx; i4 < n4; i4 += step){
    uchar4 b = ((const uchar4*)m)[i4];
    c0 += (b.y != 0) + (b.z != 0) + (b.w != 0);
    c1 += (b.x > 1) + (b.y > 1) + (b.z > 1) + (b.w > 1);
    c2 += (b.y != 0);
  }
  #pragma unroll
  for (int o = 32; o >= 1; o >>= 1){
    c0 += __shfl_xor(c0, o); c1 += __shfl_xor(c1, o); c2 += __shfl_xor(c2, o);
  }
  if ((threadIdx.x & 63) == 0){
    atomicAdd(&cnt[0], c0); atomicAdd(&cnt[1], c1); atomicAdd(&cnt[2], c2);
  }
}

// ---------------- fused f32 -> bf16 conversion (6 tensors) ----------------
// enc-sized segments: 2,097,152 chunks of 8; W-sized: 524,288 chunks of 8.
__global__ __launch_bounds__(256)
void cvt6(const float* __restrict__ s0, const float* __restrict__ s1,
          const float* __restrict__ s2, const float* __restrict__ s3,
          const float* __restrict__ s4, const float* __restrict__ s5,
          unsigned short* __restrict__ d0, unsigned short* __restrict__ d1,
          unsigned short* __restrict__ d2, unsigned short* __restrict__ d3,
          unsigned short* __restrict__ d4, unsigned short* __restrict__ d5)
{
  const long total = 7864320;  // 3*2097152 + 3*524288
  for (long c = (long)blockIdx.x * blockDim.x + threadIdx.x; c < total;
       c += (long)gridDim.x * blockDim.x){
    const float* s; unsigned short* d; long off;
    if      (c < 2097152){ s = s0; d = d0; off = c; }
    else if (c < 4194304){ s = s1; d = d1; off = c - 2097152; }
    else if (c < 6291456){ s = s2; d = d2; off = c - 4194304; }
    else if (c < 6815744){ s = s3; d = d3; off = c - 6291456; }
    else if (c < 7340032){ s = s4; d = d4; off = c - 6815744; }
    else                 { s = s5; d = d5; off = c - 7340032; }
    f32x4 a = ((const f32x4*)s)[off * 2];
    f32x4 b = ((const f32x4*)s)[off * 2 + 1];
    ushort8 w;
    #pragma unroll
    for (int j = 0; j < 4; ++j){ w[j] = f2bf(a[j]); w[j + 4] = f2bf(b[j]); }
    ((ushort8*)d)[off] = w;
  }
}

// ---------------- NT GEMM body: C[m,n] = sum_k A[m,k]*B[n,k] ----------------
// 128x128 tile, BK=32, 4 waves, 16x16x32 bf16 MFMA, double-buffered LDS,
// one barrier per K-step. AMODE/BMODE 0 = bf16 via global_load_lds(16B);
// 1 = f32 reg-staged (fallback only). EPI: 0 bf16 C; 1 scale+mask bf16; 2 f32 C.
template<int AMODE, int BMODE, int EPI>
__device__ __forceinline__ void gemm_body(
    const void* __restrict__ Av, const void* __restrict__ Bv,
    void* __restrict__ Cb, const void* __restrict__ mask, const int* __restrict__ cnt,
    int bz, long Abs, long Bbs, long Cbs, long tm, long tn, float scale,
    unsigned short (*lA)[4096], unsigned short (*lB)[4096])
{
  constexpr int K = 2048, LD = 2048;
  const int tid = threadIdx.x, lane = tid & 63, wave = tid >> 6;
  const int wr = wave >> 1, wc = wave & 1;
  const int c0 = tid, c1 = tid + 256;
  const int r0 = c0 >> 2, q0 = (c0 & 3) * 8;
  const int r1 = c1 >> 2, q1 = (c1 & 3) * 8;

  const unsigned short* A16 = (const unsigned short*)Av + (long)bz * Abs;
  const unsigned short* B16 = (const unsigned short*)Bv + (long)bz * Bbs;
  const float*          A32 = (const float*)Av + (long)bz * Abs;
  const float*          B32 = (const float*)Bv + (long)bz * Bbs;

  f32x4 acc[4][4] = {};
  f32x4 sA[4], sB[4];

  auto issueA = [&](int buf, int kk){
    if constexpr (AMODE == 0){
      __builtin_amdgcn_global_load_lds((const AS1 void*)(A16 + (tm + r0) * LD + q0 + kk),
                                       (AS3 void*)(lA[buf] + c0 * 8), 16, 0, 0);
      __builtin_amdgcn_global_load_lds((const AS1 void*)(A16 + (tm + r1) * LD + q1 + kk),
                                       (AS3 void*)(lA[buf] + c1 * 8), 16, 0, 0);
    } else {
      sA[0] = *(const f32x4*)(A32 + (tm + r0) * LD + q0 + kk);
      sA[1] = *(const f32x4*)(A32 + (tm + r0) * LD + q0 + kk + 4);
      sA[2] = *(const f32x4*)(A32 + (tm + r1) * LD + q1 + kk);
      sA[3] = *(const f32x4*)(A32 + (tm + r1) * LD + q1 + kk + 4);
    }
  };
  auto issueB = [&](int buf, int kk){
    if constexpr (BMODE == 0){
      __builtin_amdgcn_global_load_lds((const AS1 void*)(B16 + (tn + r0) * LD + q0 + kk),
                                       (AS3 void*)(lB[buf] + c0 * 8), 16, 0, 0);
      __builtin_amdgcn_global_load_lds((const AS1 void*)(B16 + (tn + r1) * LD + q1 + kk),
                                       (AS3 void*)(lB[buf] + c1 * 8), 16, 0, 0);
    } else {
      sB[0] = *(const f32x4*)(B32 + (tn + r0) * LD + q0 + kk);
      sB[1] = *(const f32x4*)(B32 + (tn + r0) * LD + q0 + kk + 4);
      sB[2] = *(const f32x4*)(B32 + (tn + r1) * LD + q1 + kk);
      sB[3] = *(const f32x4*)(B32 + (tn + r1) * LD + q1 + kk + 4);
    }
  };
  auto writeA = [&](int buf){
    if constexpr (AMODE == 1){
      ushort8 w0, w1;
      #pragma unroll
      for (int j = 0; j < 4; ++j){
        w0[j] = f2bf(sA[0][j]); w0[j + 4] = f2bf(sA[1][j]);
        w1[j] = f2bf(sA[2][j]); w1[j + 4] = f2bf(sA[3][j]);
      }
      *(ushort8*)(lA[buf] + c0 * 8) = w0;
      *(ushort8*)(lA[buf] + c1 * 8) = w1;
    }
  };
  auto writeB = [&](int buf){
    if constexpr (BMODE == 1){
      ushort8 w0, w1;
      #pragma unroll
      for (int j = 0; j < 4; ++j){
        w0[j] = f2bf(sB[0][j]); w0[j + 4] = f2bf(sB[1][j]);
        w1[j] = f2bf(sB[2][j]); w1[j + 4] = f2bf(sB[3][j]);
      }
      *(ushort8*)(lB[buf] + c0 * 8) = w0;
      *(ushort8*)(lB[buf] + c1 * 8) = w1;
    }
  };
  auto computeTile = [&](int buf){
    short8 aF[4], bF[4];
    #pragma unroll
    for (int m = 0; m < 4; ++m)
      aF[m] = *(const short8*)(lA[buf] + (wr * 64 + m * 16 + (lane & 15)) * 32 + (lane >> 4) * 8);
    #pragma unroll
    for (int n = 0; n < 4; ++n)
      bF[n] = *(const short8*)(lB[buf] + (wc * 64 + n * 16 + (lane & 15)) * 32 + (lane >> 4) * 8);
    #pragma unroll
    for (int m = 0; m < 4; ++m)
      #pragma unroll
      for (int n = 0; n < 4; ++n)
        acc[m][n] = __builtin_amdgcn_mfma_f32_16x16x32_bf16(aF[m], bF[n], acc[m][n], 0, 0, 0);
  };

  issueA(0, 0); issueB(0, 0); writeA(0); writeB(0);
  __syncthreads();
  int cur = 0;
  for (int k0 = 0; k0 < K - 32; k0 += 32){
    issueA(cur ^ 1, k0 + 32);
    issueB(cur ^ 1, k0 + 32);
    computeTile(cur);
    writeA(cur ^ 1); writeB(cur ^ 1);
    __syncthreads();
    cur ^= 1;
  }
  computeTile(cur);

  // C/D layout (m89-verified): col = lane&15, row = (lane>>4)*4 + j
  const int colo = lane & 15, rowg = (lane >> 4) * 4;
  if constexpr (EPI == 0){
    unsigned short* C = (unsigned short*)Cb + (long)bz * Cbs;
    #pragma unroll
    for (int m = 0; m < 4; ++m)
      #pragma unroll
      for (int j = 0; j < 4; ++j){
        const long row = tm + wr * 64 + m * 16 + rowg + j;
        unsigned short* cr = C + row * LD + tn + wc * 64 + colo;
        #pragma unroll
        for (int n = 0; n < 4; ++n) cr[n * 16] = f2bf(acc[m][n][j]);
      }
  } else if constexpr (EPI == 2){
    float* C = (float*)Cb + (long)bz * Cbs;
    #pragma unroll
    for (int m = 0; m < 4; ++m)
      #pragma unroll
      for (int j = 0; j < 4; ++j){
        const long row = tm + wr * 64 + m * 16 + rowg + j;
        float* cr = C + row * LD + tn + wc * 64 + colo;
        #pragma unroll
        for (int n = 0; n < 4; ++n) cr[n * 16] = acc[m][n][j];
      }
  } else {
    const int a0 = cnt[0], a1 = cnt[1], a2 = cnt[2];
    const int mmode = (a1 == 0) ? (a0 > 1000 ? 0 : 1) : (a2 > 1000 ? 2 : 3);
    unsigned short* C = (unsigned short*)Cb + (long)bz * Cbs;
    const long mbase = (long)bz * SQL * SKL;
    #pragma unroll
    for (int m = 0; m < 4; ++m)
      #pragma unroll
      for (int j = 0; j < 4; ++j){
        const long row = tm + wr * 64 + m * 16 + rowg + j;
        #pragma unroll
        for (int n = 0; n < 4; ++n){
          const long col = tn + wc * 64 + n * 16 + colo;
          const long midx = mbase + row * SKL + col;
          bool msk;
          if (mmode == 0)      msk = ((const uint8_t*)mask)[midx] != 0;
          else if (mmode == 1) msk = ((const int*)mask)[midx] != 0;
          else if (mmode == 2) msk = ((const unsigned short*)mask)[midx] != 0;
          else                 msk = ((const uint32_t*)mask)[midx] != 0;
          float vv = acc[m][n][j] * scale;
          if (msk) vv = NEGV;
          C[row * SKL + col] = f2bf(vv);
        }
      }
  }
}

// bijective XCD swizzle (nwg % 8 == 0 for all our grids)
__device__ __forceinline__ void xcd_decode(int& bx, int& by, int& bz){
  const int gx = gridDim.x, gy = gridDim.y;
  const int nwg = gx * gy * gridDim.z;
  const int lid = blockIdx.x + gx * (blockIdx.y + gy * blockIdx.z);
  const int sw  = (lid & 7) * (nwg >> 3) + (lid >> 3);
  bx = sw % gx;
  const int t = sw / gx;
  by = t % gy;
  bz = t / gy;
}

template<int AMODE, int BMODE, int EPI>
__global__ __launch_bounds__(256, 2)
void gemm_nt(const void* __restrict__ Abv, const void* __restrict__ Bbv,
             void* __restrict__ Cb, const void* __restrict__ mask,
             const int* __restrict__ cnt,
             long Abs, long Bbs, long Cbs, float scale)
{
  __shared__ unsigned short lA[2][4096];
  __shared__ unsigned short lB[2][4096];
  int bx, by, bz; xcd_decode(bx, by, bz);
  gemm_body<AMODE, BMODE, EPI>(Abv, Bbv, Cb, mask, cnt, bz, Abs, Bbs, Cbs,
                               (long)by * 128, (long)bx * 128, scale, lA, lB);
}

// all three projections fused: z 0-3 -> Q, 4-7 -> K', 8-11 -> V^T
// MODE 0: all operands bf16; MODE 1: f32 reg-staged (fallback)
template<int MODE>
__global__ __launch_bounds__(256, 2)
void gemm_proj3(const void* A0, const void* A1, const void* A2,
                const void* B0, const void* B1, const void* B2,
                void* C0, void* C1, void* C2)
{
  __shared__ unsigned short lA[2][4096];
  __shared__ unsigned short lB[2][4096];
  int bx, by, bz; xcd_decode(bx, by, bz);
  const int sec = bz >> 2, b = bz & 3;
  const long NN = (long)SQL * 2048;
  const void* Av = sec == 0 ? A0 : sec == 1 ? A1 : A2;
  const void* Bv = sec == 0 ? B0 : sec == 1 ? B1 : B2;
  void*       Cv = sec == 0 ? C0 : sec == 1 ? C1 : C2;
  const long Abs = (sec == 2) ? 0 : NN;
  const long Bbs = (sec == 2) ? NN : 0;
  gemm_body<MODE, MODE, 0>(Av, Bv, Cv, nullptr, nullptr, b, Abs, Bbs, NN,
                           (long)by * 128, (long)bx * 128, 1.f, lA, lB);
}

// ---------------- row softmax: S bf16 [row,0..2047] -> P bf16 ----------------
__global__ __launch_bounds__(256, 4)
void softmax_rows(const unsigned short* __restrict__ S, unsigned short* __restrict__ P){
  const long row = blockIdx.x;
  const int t = threadIdx.x;
  ushort8 u = *((const ushort8*)(S + row * SKL) + t);
  float v[8];
  #pragma unroll
  for (int j = 0; j < 8; ++j) v[j] = bf2f(u[j]);
  float mx = v[0];
  #pragma unroll
  for (int j = 1; j < 8; ++j) mx = fmaxf(mx, v[j]);
  #pragma unroll
  for (int o = 32; o >= 1; o >>= 1) mx = fmaxf(mx, __shfl_xor(mx, o));
  __shared__ float red[8];
  const int wv = t >> 6, ln = t & 63;
  if (ln == 0) red[wv] = mx;
  __syncthreads();
  mx = fmaxf(fmaxf(red[0], red[1]), fmaxf(red[2], red[3]));
  float e[8], sum = 0.f;
  #pragma unroll
  for (int j = 0; j < 8; ++j){ e[j] = exp2f((v[j] - mx) * 1.4426950408889634f); sum += e[j]; }
  #pragma unroll
  for (int o = 32; o >= 1; o >>= 1) sum += __shfl_xor(sum, o);
  if (ln == 0) red[4 + wv] = sum;
  __syncthreads();
  sum = red[4] + red[5] + red[6] + red[7];
  const float inv = 1.0f / sum;
  ushort8 o8;
  #pragma unroll
  for (int j = 0; j < 8; ++j) o8[j] = f2bf(e[j] * inv);
  *((ushort8*)(P + row * SKL) + t) = o8;
}

// ---------------- host ----------------
extern "C" void kernel_launch(void* const* d_in, const int* in_sizes, int n_in,
                              void* d_out, int out_size, void* d_ws, size_t ws_size,
                              hipStream_t stream)
{
  (void)in_sizes; (void)n_in; (void)out_size;
  const void* x    = d_in[0];   // f32 [B,SKV,D]
  const void* encq = d_in[1];   // f32 [B,SQ,D]
  const void* enck = d_in[2];   // f32 [B,SKV,D]
  const void* imsk = d_in[3];   // bool-ish [B,SQ,SKV] (sniffed)
  const void* Wq   = d_in[4];   // f32 [D,D]
  const void* Wk   = d_in[5];
  const void* Wv   = d_in[6];

  uint8_t* ws = (uint8_t*)d_ws;
  int* cnt = (int*)ws;                                   // 4 KiB
  const long NN = (long)2048 * 2048;                     // 4,194,304
  const float scale = 0.022097086912079608f;             // 1/sqrt(2048)
  dim3 blk(256);

  hipMemsetAsync(cnt, 0, 4096, stream);
  mask_detect<<<256, 256, 0, stream>>>((const uint8_t*)imsk, cnt);

  // Full plan: bf16 copies of all inputs in ws; Q and S in the two 32MiB
  // halves of d_out (both dead before PV overwrites d_out with f32 output).
  const size_t ENC = 33554432, WSZ = 8388608;            // bytes (bf16)
  const size_t FULL_NEED = 4096 + 3 * ENC + 3 * WSZ + 2 * ENC;  // 192,942,080
  if (ws_size >= FULL_NEED){
    unsigned short* xb  = (unsigned short*)(ws + 4096);
    unsigned short* qb  = xb + 16777216;
    unsigned short* kb  = qb + 16777216;
    unsigned short* Wqb = kb + 16777216;
    unsigned short* Wkb = Wqb + 4194304;
    unsigned short* Wvb = Wkb + 4194304;
    unsigned short* Kp  = Wvb + 4194304;
    unsigned short* Vt  = Kp + 16777216;
    unsigned short* Q   = (unsigned short*)d_out;         // [0, 32MiB)
    unsigned short* S   = Q + 16777216;                   // [32MiB, 64MiB)
    unsigned short* P   = qb;                             // qb dead after Q-proj

    cvt6<<<2048, blk, 0, stream>>>((const float*)x, (const float*)encq, (const float*)enck,
                                   (const float*)Wq, (const float*)Wk, (const float*)Wv,
                                   xb, qb, kb, Wqb, Wkb, Wvb);
    gemm_proj3<0><<<dim3(16, 16, 12), blk, 0, stream>>>(qb, kb, Wvb, Wqb, Wkb, xb, Q, Kp, Vt);
    gemm_nt<0, 0, 1><<<dim3(16, 16, BB), blk, 0, stream>>>(Q, Kp, S, imsk, cnt, NN, NN, NN, scale);
    softmax_rows<<<BB * SQL, 256, 0, stream>>>(S, P);
    gemm_nt<0, 0, 2><<<dim3(16, 16, BB), blk, 0, stream>>>(P, Vt, d_out, nullptr, cnt, NN, NN, NN, 1.f);
  } else {
    // Fallback (round-3 path): f32 reg-staged projections.
    unsigned short* Q  = (unsigned short*)(ws + 4096);
    unsigned short* Kp = Q  + 16777216;
    unsigned short* Vt = Kp + 16777216;
    unsigned short* P  = Q;
    unsigned short* S;
    const size_t need = 4096 + 4ull * 33554432;
    if (ws_size >= need) S = Vt + 16777216;
    else                 S = (unsigned short*)d_out;

    gemm_proj3<1><<<dim3(16, 16, 12), blk, 0, stream>>>(encq, enck, Wv, Wq, Wk, x, Q, Kp, Vt);
    gemm_nt<0, 0, 1><<<dim3(16, 16, BB), blk, 0, stream>>>(Q, Kp, S, imsk, cnt, NN, NN, NN, scale);
    softmax_rows<<<BB * SQL, 256, 0, stream>>>(S, P);
    gemm_nt<0, 0, 2><<<dim3(16, 16, BB), blk, 0, stream>>>(P, Vt, d_out, nullptr, cnt, NN, NN, NN, 1.f);
  }
}

// Round 5
// 543.369 us; speedup vs baseline: 1.4715x; 1.0554x over previous
//
#include <hip/hip_runtime.h>
#include <stdint.h>

typedef short  short8  __attribute__((ext_vector_type(8)));
typedef unsigned short ushort8 __attribute__((ext_vector_type(8)));
typedef float  f32x4   __attribute__((ext_vector_type(4)));

#define BB  4
#define SQL 2048
#define SKL 2048
#define NEGV -1e9f
#define AS1 __attribute__((address_space(1)))
#define AS3 __attribute__((address_space(3)))

__device__ __forceinline__ unsigned short f2bf(float f){
  union { float f; uint32_t u; } x; x.f = f;
  return (unsigned short)((x.u + 0x7FFFu + ((x.u >> 16) & 1u)) >> 16);
}
__device__ __forceinline__ float bf2f(unsigned short h){
  union { uint32_t u; float f; } x; x.u = ((uint32_t)h) << 16;
  return x.f;
}

#define BARR() __builtin_amdgcn_s_barrier()
#define LGKM0() { asm volatile("s_waitcnt lgkmcnt(0)" ::: "memory"); __builtin_amdgcn_sched_barrier(0); }
#define VM0()   { asm volatile("s_waitcnt vmcnt(0)"   ::: "memory"); __builtin_amdgcn_sched_barrier(0); }

// ---------------- mask dtype sniffing ----------------
__global__ void mask_detect(const uint8_t* __restrict__ m, int* __restrict__ cnt){
  const long n4 = (long)BB * SQL * SKL / 4;
  long idx  = (long)blockIdx.x * blockDim.x + threadIdx.x;
  long step = (long)gridDim.x * blockDim.x;
  int c0 = 0, c1 = 0, c2 = 0;
  for (long i4 = idx; i4 < n4; i4 += step){
    uchar4 b = ((const uchar4*)m)[i4];
    c0 += (b.y != 0) + (b.z != 0) + (b.w != 0);
    c1 += (b.x > 1) + (b.y > 1) + (b.z > 1) + (b.w > 1);
    c2 += (b.y != 0);
  }
  #pragma unroll
  for (int o = 32; o >= 1; o >>= 1){
    c0 += __shfl_xor(c0, o); c1 += __shfl_xor(c1, o); c2 += __shfl_xor(c2, o);
  }
  if ((threadIdx.x & 63) == 0){
    atomicAdd(&cnt[0], c0); atomicAdd(&cnt[1], c1); atomicAdd(&cnt[2], c2);
  }
}

// ---------------- fused f32 -> bf16 conversion (6 tensors) ----------------
__global__ __launch_bounds__(256)
void cvt6(const float* __restrict__ s0, const float* __restrict__ s1,
          const float* __restrict__ s2, const float* __restrict__ s3,
          const float* __restrict__ s4, const float* __restrict__ s5,
          unsigned short* __restrict__ d0, unsigned short* __restrict__ d1,
          unsigned short* __restrict__ d2, unsigned short* __restrict__ d3,
          unsigned short* __restrict__ d4, unsigned short* __restrict__ d5)
{
  const long total = 7864320;  // 3*2097152 + 3*524288
  for (long c = (long)blockIdx.x * blockDim.x + threadIdx.x; c < total;
       c += (long)gridDim.x * blockDim.x){
    const float* s; unsigned short* d; long off;
    if      (c < 2097152){ s = s0; d = d0; off = c; }
    else if (c < 4194304){ s = s1; d = d1; off = c - 2097152; }
    else if (c < 6291456){ s = s2; d = d2; off = c - 4194304; }
    else if (c < 6815744){ s = s3; d = d3; off = c - 6291456; }
    else if (c < 7340032){ s = s4; d = d4; off = c - 6815744; }
    else                 { s = s5; d = d5; off = c - 7340032; }
    f32x4 a = ((const f32x4*)s)[off * 2];
    f32x4 b = ((const f32x4*)s)[off * 2 + 1];
    ushort8 w;
    #pragma unroll
    for (int j = 0; j < 4; ++j){ w[j] = f2bf(a[j]); w[j + 4] = f2bf(b[j]); }
    ((ushort8*)d)[off] = w;
  }
}

// ============ 256x256 8-phase NT GEMM (m201 template, plain HIP) ============
// BM=BN=256, BK=64, 8 waves (2Mx4N), 512 threads, 128 KiB LDS dbuf.
// LDS granule swizzle: granule g at row r holds global granule g^(r&7)
// (pre-swizzled global source + swizzled ds_read, both-sides involution).
// Per K-tile: 4 phases {ds_read || stage || bar; lgkm0; setprio1; 16 MFMA;
// setprio0; bar}, vmcnt(0) once per K-tile (end ph4, 2-3 phases of cover).
template<int EPI>
__device__ __forceinline__ void gemm256_body(
    const unsigned short* __restrict__ Ag, const unsigned short* __restrict__ Bg,
    void* __restrict__ Cb, const void* __restrict__ mask, const int* __restrict__ cnt,
    int bz, long Cbs, long tm, long tn, float scale,
    unsigned short (&lA)[2][16384], unsigned short (&lB)[2][16384])
{
  constexpr int LD = 2048;
  const int tid = threadIdx.x, lane = tid & 63, wid = tid >> 6;
  const int wm = wid >> 2, wn = wid & 3;
  const int l15 = lane & 15, l16 = lane >> 4;

  f32x4 acc[8][4] = {};

  // stage one full 256x64 operand tile (4 x global_load_lds of 16B/thread)
  auto stage = [&](unsigned short* dst, const unsigned short* src, long tbase, int k){
    #pragma unroll
    for (int l = 0; l < 4; ++l){
      const int idx = l * 512 + tid;          // granule index 0..2047
      const int row = idx >> 3;
      const int gsw = (idx & 7) ^ (row & 7);  // inverse-swizzled global source
      __builtin_amdgcn_global_load_lds(
        (const AS1 void*)(src + (tbase + row) * LD + k + gsw * 8),
        (AS3 void*)(dst + idx * 8), 16, 0, 0);
    }
  };

  short8 aF[4], bF[4];
  // swizzled ds_read of one 16x32 fragment (8 bf16/lane)
  #define RDA(BUF, MH, KS)                                                    \
    _Pragma("unroll")                                                         \
    for (int j = 0; j < 4; ++j){                                              \
      const int fr = wm * 128 + ((MH) * 4 + j) * 16 + l15;                    \
      const int g  = (KS) * 4 + l16;                                          \
      aF[j] = *(const short8*)&lA[BUF][(fr * 8 + (g ^ (fr & 7))) * 8];        \
    }
  #define RDB(BUF, KS)                                                        \
    _Pragma("unroll")                                                         \
    for (int j = 0; j < 4; ++j){                                              \
      const int fn = wn * 64 + j * 16 + l15;                                  \
      const int g  = (KS) * 4 + l16;                                          \
      bF[j] = *(const short8*)&lB[BUF][(fn * 8 + (g ^ (fn & 7))) * 8];        \
    }
  #define MFMA16(MH)                                                          \
    _Pragma("unroll")                                                         \
    for (int j = 0; j < 4; ++j){                                              \
      _Pragma("unroll")                                                       \
      for (int n = 0; n < 4; ++n)                                             \
        acc[(MH) * 4 + j][n] = __builtin_amdgcn_mfma_f32_16x16x32_bf16(       \
            aF[j], bF[n], acc[(MH) * 4 + j][n], 0, 0, 0);                     \
    }

  #define KTILE(BUF, KST, DOSTAGE)                                            \
  {                                                                           \
    /* ph1: ks0 mh0 ; stage next A */                                         \
    RDB(BUF, 0); RDA(BUF, 0, 0);                                              \
    if (DOSTAGE) stage(lA[(BUF) ^ 1], Ag, tm, (KST));                         \
    BARR(); LGKM0();                                                          \
    __builtin_amdgcn_s_setprio(1); MFMA16(0); __builtin_amdgcn_s_setprio(0);  \
    BARR();                                                                   \
    /* ph2: ks0 mh1 ; stage next B */                                         \
    RDA(BUF, 1, 0);                                                           \
    if (DOSTAGE) stage(lB[(BUF) ^ 1], Bg, tn, (KST));                         \
    BARR(); LGKM0();                                                          \
    __builtin_amdgcn_s_setprio(1); MFMA16(1); __builtin_amdgcn_s_setprio(0);  \
    BARR();                                                                   \
    /* ph3: ks1 mh0 */                                                        \
    RDB(BUF, 1); RDA(BUF, 0, 1);                                              \
    BARR(); LGKM0();                                                          \
    __builtin_amdgcn_s_setprio(1); MFMA16(0); __builtin_amdgcn_s_setprio(0);  \
    BARR();                                                                   \
    /* ph4: ks1 mh1 ; drain this tile's prefetch before next buf flips */     \
    RDA(BUF, 1, 1);                                                           \
    BARR(); LGKM0();                                                          \
    __builtin_amdgcn_s_setprio(1); MFMA16(1); __builtin_amdgcn_s_setprio(0);  \
    VM0();                                                                    \
    BARR();                                                                   \
  }

  // prologue: stage tile 0 into buf 0
  stage(lA[0], Ag, tm, 0);
  stage(lB[0], Bg, tn, 0);
  VM0(); BARR();

  for (int it = 0; it < 16; ++it){
    KTILE(0, (2 * it + 1) * 64, true);       // compute tile 2it, stage 2it+1 -> buf1
    KTILE(1, (2 * it + 2) * 64, it < 15);    // compute tile 2it+1, stage 2it+2 -> buf0
  }

  // ---- epilogue ---- C/D layout: col = lane&15, row = (lane>>4)*4 + j
  const int colo = l15, rowg = l16 * 4;
  if constexpr (EPI == 0){
    unsigned short* C = (unsigned short*)Cb + (long)bz * Cbs;
    #pragma unroll
    for (int m = 0; m < 8; ++m)
      #pragma unroll
      for (int j = 0; j < 4; ++j){
        const long row = tm + wm * 128 + m * 16 + rowg + j;
        unsigned short* cr = C + row * LD + tn + wn * 64 + colo;
        #pragma unroll
        for (int n = 0; n < 4; ++n) cr[n * 16] = f2bf(acc[m][n][j]);
      }
  } else if constexpr (EPI == 2){
    float* C = (float*)Cb + (long)bz * Cbs;
    #pragma unroll
    for (int m = 0; m < 8; ++m)
      #pragma unroll
      for (int j = 0; j < 4; ++j){
        const long row = tm + wm * 128 + m * 16 + rowg + j;
        float* cr = C + row * LD + tn + wn * 64 + colo;
        #pragma unroll
        for (int n = 0; n < 4; ++n) cr[n * 16] = acc[m][n][j];
      }
  } else {
    const int a0 = cnt[0], a1 = cnt[1], a2 = cnt[2];
    const int mmode = (a1 == 0) ? (a0 > 1000 ? 0 : 1) : (a2 > 1000 ? 2 : 3);
    unsigned short* C = (unsigned short*)Cb + (long)bz * Cbs;
    const long mbase = (long)bz * SQL * SKL;
    #pragma unroll
    for (int m = 0; m < 8; ++m)
      #pragma unroll
      for (int j = 0; j < 4; ++j){
        const long row = tm + wm * 128 + m * 16 + rowg + j;
        #pragma unroll
        for (int n = 0; n < 4; ++n){
          const long col = tn + wn * 64 + n * 16 + colo;
          const long midx = mbase + row * SKL + col;
          bool msk;
          if (mmode == 0)      msk = ((const uint8_t*)mask)[midx] != 0;
          else if (mmode == 1) msk = ((const int*)mask)[midx] != 0;
          else if (mmode == 2) msk = ((const unsigned short*)mask)[midx] != 0;
          else                 msk = ((const uint32_t*)mask)[midx] != 0;
          float vv = acc[m][n][j] * scale;
          if (msk) vv = NEGV;
          C[row * SKL + col] = f2bf(vv);
        }
      }
  }
  #undef RDA
  #undef RDB
  #undef MFMA16
  #undef KTILE
}

// bijective XCD swizzle (nwg % 8 == 0 for all our grids)
__device__ __forceinline__ void xcd_decode(int& bx, int& by, int& bz){
  const int gx = gridDim.x, gy = gridDim.y;
  const int nwg = gx * gy * gridDim.z;
  const int lid = blockIdx.x + gx * (blockIdx.y + gy * blockIdx.z);
  const int sw  = (lid & 7) * (nwg >> 3) + (lid >> 3);
  bx = sw % gx;
  const int t = sw / gx;
  by = t % gy;
  bz = t / gy;
}

template<int EPI>
__global__ __launch_bounds__(512, 2)
void gemm256(const unsigned short* __restrict__ A, const unsigned short* __restrict__ B,
             void* __restrict__ Cb, const void* __restrict__ mask,
             const int* __restrict__ cnt, long Abs, long Bbs, long Cbs, float scale)
{
  __shared__ unsigned short lA[2][16384];
  __shared__ unsigned short lB[2][16384];
  int bx, by, bz; xcd_decode(bx, by, bz);
  gemm256_body<EPI>(A + (long)bz * Abs, B + (long)bz * Bbs, Cb, mask, cnt, bz, Cbs,
                    (long)by * 256, (long)bx * 256, scale, lA, lB);
}

// three projections fused, 256^2 tiles: z 0-3 -> Q, 4-7 -> K', 8-11 -> V^T
__global__ __launch_bounds__(512, 2)
void gemm256_proj3(const unsigned short* A0, const unsigned short* A1, const unsigned short* A2,
                   const unsigned short* B0, const unsigned short* B1, const unsigned short* B2,
                   void* C0, void* C1, void* C2)
{
  __shared__ unsigned short lA[2][16384];
  __shared__ unsigned short lB[2][16384];
  int bx, by, bz; xcd_decode(bx, by, bz);
  const int sec = bz >> 2, b = bz & 3;
  const long NN = (long)SQL * 2048;
  const unsigned short* Av = sec == 0 ? A0 : sec == 1 ? A1 : A2;
  const unsigned short* Bv = sec == 0 ? B0 : sec == 1 ? B1 : B2;
  void*                 Cv = sec == 0 ? C0 : sec == 1 ? C1 : C2;
  const long Abs = (sec == 2) ? 0 : NN;
  const long Bbs = (sec == 2) ? NN : 0;
  gemm256_body<0>(Av + (long)b * Abs, Bv + (long)b * Bbs, Cv, nullptr, nullptr, b, NN,
                  (long)by * 256, (long)bx * 256, 1.f, lA, lB);
}

// ============ fallback 128x128 4-wave GEMM (round-4, proven) ============
template<int AMODE, int BMODE, int EPI>
__device__ __forceinline__ void gemm_body(
    const void* __restrict__ Av, const void* __restrict__ Bv,
    void* __restrict__ Cb, const void* __restrict__ mask, const int* __restrict__ cnt,
    int bz, long Abs, long Bbs, long Cbs, long tm, long tn, float scale,
    unsigned short (*lA)[4096], unsigned short (*lB)[4096])
{
  constexpr int K = 2048, LD = 2048;
  const int tid = threadIdx.x, lane = tid & 63, wave = tid >> 6;
  const int wr = wave >> 1, wc = wave & 1;
  const int c0 = tid, c1 = tid + 256;
  const int r0 = c0 >> 2, q0 = (c0 & 3) * 8;
  const int r1 = c1 >> 2, q1 = (c1 & 3) * 8;

  const unsigned short* A16 = (const unsigned short*)Av + (long)bz * Abs;
  const unsigned short* B16 = (const unsigned short*)Bv + (long)bz * Bbs;
  const float*          A32 = (const float*)Av + (long)bz * Abs;
  const float*          B32 = (const float*)Bv + (long)bz * Bbs;

  f32x4 acc[4][4] = {};
  f32x4 sA[4], sB[4];

  auto issueA = [&](int buf, int kk){
    if constexpr (AMODE == 0){
      __builtin_amdgcn_global_load_lds((const AS1 void*)(A16 + (tm + r0) * LD + q0 + kk),
                                       (AS3 void*)(lA[buf] + c0 * 8), 16, 0, 0);
      __builtin_amdgcn_global_load_lds((const AS1 void*)(A16 + (tm + r1) * LD + q1 + kk),
                                       (AS3 void*)(lA[buf] + c1 * 8), 16, 0, 0);
    } else {
      sA[0] = *(const f32x4*)(A32 + (tm + r0) * LD + q0 + kk);
      sA[1] = *(const f32x4*)(A32 + (tm + r0) * LD + q0 + kk + 4);
      sA[2] = *(const f32x4*)(A32 + (tm + r1) * LD + q1 + kk);
      sA[3] = *(const f32x4*)(A32 + (tm + r1) * LD + q1 + kk + 4);
    }
  };
  auto issueB = [&](int buf, int kk){
    if constexpr (BMODE == 0){
      __builtin_amdgcn_global_load_lds((const AS1 void*)(B16 + (tn + r0) * LD + q0 + kk),
                                       (AS3 void*)(lB[buf] + c0 * 8), 16, 0, 0);
      __builtin_amdgcn_global_load_lds((const AS1 void*)(B16 + (tn + r1) * LD + q1 + kk),
                                       (AS3 void*)(lB[buf] + c1 * 8), 16, 0, 0);
    } else {
      sB[0] = *(const f32x4*)(B32 + (tn + r0) * LD + q0 + kk);
      sB[1] = *(const f32x4*)(B32 + (tn + r0) * LD + q0 + kk + 4);
      sB[2] = *(const f32x4*)(B32 + (tn + r1) * LD + q1 + kk);
      sB[3] = *(const f32x4*)(B32 + (tn + r1) * LD + q1 + kk + 4);
    }
  };
  auto writeA = [&](int buf){
    if constexpr (AMODE == 1){
      ushort8 w0, w1;
      #pragma unroll
      for (int j = 0; j < 4; ++j){
        w0[j] = f2bf(sA[0][j]); w0[j + 4] = f2bf(sA[1][j]);
        w1[j] = f2bf(sA[2][j]); w1[j + 4] = f2bf(sA[3][j]);
      }
      *(ushort8*)(lA[buf] + c0 * 8) = w0;
      *(ushort8*)(lA[buf] + c1 * 8) = w1;
    }
  };
  auto writeB = [&](int buf){
    if constexpr (BMODE == 1){
      ushort8 w0, w1;
      #pragma unroll
      for (int j = 0; j < 4; ++j){
        w0[j] = f2bf(sB[0][j]); w0[j + 4] = f2bf(sB[1][j]);
        w1[j] = f2bf(sB[2][j]); w1[j + 4] = f2bf(sB[3][j]);
      }
      *(ushort8*)(lB[buf] + c0 * 8) = w0;
      *(ushort8*)(lB[buf] + c1 * 8) = w1;
    }
  };
  auto computeTile = [&](int buf){
    short8 aF[4], bF[4];
    #pragma unroll
    for (int m = 0; m < 4; ++m)
      aF[m] = *(const short8*)(lA[buf] + (wr * 64 + m * 16 + (lane & 15)) * 32 + (lane >> 4) * 8);
    #pragma unroll
    for (int n = 0; n < 4; ++n)
      bF[n] = *(const short8*)(lB[buf] + (wc * 64 + n * 16 + (lane & 15)) * 32 + (lane >> 4) * 8);
    #pragma unroll
    for (int m = 0; m < 4; ++m)
      #pragma unroll
      for (int n = 0; n < 4; ++n)
        acc[m][n] = __builtin_amdgcn_mfma_f32_16x16x32_bf16(aF[m], bF[n], acc[m][n], 0, 0, 0);
  };

  issueA(0, 0); issueB(0, 0); writeA(0); writeB(0);
  __syncthreads();
  int cur = 0;
  for (int k0 = 0; k0 < K - 32; k0 += 32){
    issueA(cur ^ 1, k0 + 32);
    issueB(cur ^ 1, k0 + 32);
    computeTile(cur);
    writeA(cur ^ 1); writeB(cur ^ 1);
    __syncthreads();
    cur ^= 1;
  }
  computeTile(cur);

  const int colo = lane & 15, rowg = (lane >> 4) * 4;
  if constexpr (EPI == 0){
    unsigned short* C = (unsigned short*)Cb + (long)bz * Cbs;
    #pragma unroll
    for (int m = 0; m < 4; ++m)
      #pragma unroll
      for (int j = 0; j < 4; ++j){
        const long row = tm + wr * 64 + m * 16 + rowg + j;
        unsigned short* cr = C + row * LD + tn + wc * 64 + colo;
        #pragma unroll
        for (int n = 0; n < 4; ++n) cr[n * 16] = f2bf(acc[m][n][j]);
      }
  } else if constexpr (EPI == 2){
    float* C = (float*)Cb + (long)bz * Cbs;
    #pragma unroll
    for (int m = 0; m < 4; ++m)
      #pragma unroll
      for (int j = 0; j < 4; ++j){
        const long row = tm + wr * 64 + m * 16 + rowg + j;
        float* cr = C + row * LD + tn + wc * 64 + colo;
        #pragma unroll
        for (int n = 0; n < 4; ++n) cr[n * 16] = acc[m][n][j];
      }
  } else {
    const int a0 = cnt[0], a1 = cnt[1], a2 = cnt[2];
    const int mmode = (a1 == 0) ? (a0 > 1000 ? 0 : 1) : (a2 > 1000 ? 2 : 3);
    unsigned short* C = (unsigned short*)Cb + (long)bz * Cbs;
    const long mbase = (long)bz * SQL * SKL;
    #pragma unroll
    for (int m = 0; m < 4; ++m)
      #pragma unroll
      for (int j = 0; j < 4; ++j){
        const long row = tm + wr * 64 + m * 16 + rowg + j;
        #pragma unroll
        for (int n = 0; n < 4; ++n){
          const long col = tn + wc * 64 + n * 16 + colo;
          const long midx = mbase + row * SKL + col;
          bool msk;
          if (mmode == 0)      msk = ((const uint8_t*)mask)[midx] != 0;
          else if (mmode == 1) msk = ((const int*)mask)[midx] != 0;
          else if (mmode == 2) msk = ((const unsigned short*)mask)[midx] != 0;
          else                 msk = ((const uint32_t*)mask)[midx] != 0;
          float vv = acc[m][n][j] * scale;
          if (msk) vv = NEGV;
          C[row * SKL + col] = f2bf(vv);
        }
      }
  }
}

template<int AMODE, int BMODE, int EPI>
__global__ __launch_bounds__(256, 2)
void gemm_nt(const void* __restrict__ Abv, const void* __restrict__ Bbv,
             void* __restrict__ Cb, const void* __restrict__ mask,
             const int* __restrict__ cnt,
             long Abs, long Bbs, long Cbs, float scale)
{
  __shared__ unsigned short lA[2][4096];
  __shared__ unsigned short lB[2][4096];
  int bx, by, bz; xcd_decode(bx, by, bz);
  gemm_body<AMODE, BMODE, EPI>(Abv, Bbv, Cb, mask, cnt, bz, Abs, Bbs, Cbs,
                               (long)by * 128, (long)bx * 128, scale, lA, lB);
}

template<int MODE>
__global__ __launch_bounds__(256, 2)
void gemm_proj3(const void* A0, const void* A1, const void* A2,
                const void* B0, const void* B1, const void* B2,
                void* C0, void* C1, void* C2)
{
  __shared__ unsigned short lA[2][4096];
  __shared__ unsigned short lB[2][4096];
  int bx, by, bz; xcd_decode(bx, by, bz);
  const int sec = bz >> 2, b = bz & 3;
  const long NN = (long)SQL * 2048;
  const void* Av = sec == 0 ? A0 : sec == 1 ? A1 : A2;
  const void* Bv = sec == 0 ? B0 : sec == 1 ? B1 : B2;
  void*       Cv = sec == 0 ? C0 : sec == 1 ? C1 : C2;
  const long Abs = (sec == 2) ? 0 : NN;
  const long Bbs = (sec == 2) ? NN : 0;
  gemm_body<MODE, MODE, 0>(Av, Bv, Cv, nullptr, nullptr, b, Abs, Bbs, NN,
                           (long)by * 128, (long)bx * 128, 1.f, lA, lB);
}

// ---------------- row softmax: S bf16 [row,0..2047] -> P bf16 ----------------
__global__ __launch_bounds__(256, 4)
void softmax_rows(const unsigned short* __restrict__ S, unsigned short* __restrict__ P){
  const long row = blockIdx.x;
  const int t = threadIdx.x;
  ushort8 u = *((const ushort8*)(S + row * SKL) + t);
  float v[8];
  #pragma unroll
  for (int j = 0; j < 8; ++j) v[j] = bf2f(u[j]);
  float mx = v[0];
  #pragma unroll
  for (int j = 1; j < 8; ++j) mx = fmaxf(mx, v[j]);
  #pragma unroll
  for (int o = 32; o >= 1; o >>= 1) mx = fmaxf(mx, __shfl_xor(mx, o));
  __shared__ float red[8];
  const int wv = t >> 6, ln = t & 63;
  if (ln == 0) red[wv] = mx;
  __syncthreads();
  mx = fmaxf(fmaxf(red[0], red[1]), fmaxf(red[2], red[3]));
  float e[8], sum = 0.f;
  #pragma unroll
  for (int j = 0; j < 8; ++j){ e[j] = exp2f((v[j] - mx) * 1.4426950408889634f); sum += e[j]; }
  #pragma unroll
  for (int o = 32; o >= 1; o >>= 1) sum += __shfl_xor(sum, o);
  if (ln == 0) red[4 + wv] = sum;
  __syncthreads();
  sum = red[4] + red[5] + red[6] + red[7];
  const float inv = 1.0f / sum;
  ushort8 o8;
  #pragma unroll
  for (int j = 0; j < 8; ++j) o8[j] = f2bf(e[j] * inv);
  *((ushort8*)(P + row * SKL) + t) = o8;
}

// ---------------- host ----------------
extern "C" void kernel_launch(void* const* d_in, const int* in_sizes, int n_in,
                              void* d_out, int out_size, void* d_ws, size_t ws_size,
                              hipStream_t stream)
{
  (void)in_sizes; (void)n_in; (void)out_size;
  const void* x    = d_in[0];
  const void* encq = d_in[1];
  const void* enck = d_in[2];
  const void* imsk = d_in[3];
  const void* Wq   = d_in[4];
  const void* Wk   = d_in[5];
  const void* Wv   = d_in[6];

  uint8_t* ws = (uint8_t*)d_ws;
  int* cnt = (int*)ws;
  const long NN = (long)2048 * 2048;
  const float scale = 0.022097086912079608f;  // 1/sqrt(2048)

  hipMemsetAsync(cnt, 0, 4096, stream);
  mask_detect<<<256, 256, 0, stream>>>((const uint8_t*)imsk, cnt);

  const size_t ENC = 33554432, WSZ = 8388608;
  const size_t FULL_NEED = 4096 + 3 * ENC + 3 * WSZ + 2 * ENC;
  if (ws_size >= FULL_NEED){
    unsigned short* xb  = (unsigned short*)(ws + 4096);
    unsigned short* qb  = xb + 16777216;
    unsigned short* kb  = qb + 16777216;
    unsigned short* Wqb = kb + 16777216;
    unsigned short* Wkb = Wqb + 4194304;
    unsigned short* Wvb = Wkb + 4194304;
    unsigned short* Kp  = Wvb + 4194304;
    unsigned short* Vt  = Kp + 16777216;
    unsigned short* Q   = (unsigned short*)d_out;         // [0, 32MiB)
    unsigned short* S   = Q + 16777216;                   // [32MiB, 64MiB)
    unsigned short* P   = qb;                             // qb dead after Q-proj

    cvt6<<<2048, 256, 0, stream>>>((const float*)x, (const float*)encq, (const float*)enck,
                                   (const float*)Wq, (const float*)Wk, (const float*)Wv,
                                   xb, qb, kb, Wqb, Wkb, Wvb);
    gemm256_proj3<<<dim3(8, 8, 12), 512, 0, stream>>>(qb, kb, Wvb, Wqb, Wkb, xb, Q, Kp, Vt);
    gemm256<1><<<dim3(8, 8, BB), 512, 0, stream>>>(Q, Kp, S, imsk, cnt, NN, NN, NN, scale);
    softmax_rows<<<BB * SQL, 256, 0, stream>>>(S, P);
    gemm256<2><<<dim3(8, 8, BB), 512, 0, stream>>>(P, Vt, d_out, nullptr, cnt, NN, NN, NN, 1.f);
  } else {
    unsigned short* Q  = (unsigned short*)(ws + 4096);
    unsigned short* Kp = Q  + 16777216;
    unsigned short* Vt = Kp + 16777216;
    unsigned short* P  = Q;
    unsigned short* S;
    const size_t need = 4096 + 4ull * 33554432;
    if (ws_size >= need) S = Vt + 16777216;
    else                 S = (unsigned short*)d_out;

    gemm_proj3<1><<<dim3(16, 16, 12), 256, 0, stream>>>(encq, enck, Wv, Wq, Wk, x, Q, Kp, Vt);
    gemm_nt<0, 0, 1><<<dim3(16, 16, BB), 256, 0, stream>>>(Q, Kp, S, imsk, cnt, NN, NN, NN, scale);
    softmax_rows<<<BB * SQL, 256, 0, stream>>>(S, P);
    gemm_nt<0, 0, 2><<<dim3(16, 16, BB), 256, 0, stream>>>(P, Vt, d_out, nullptr, cnt, NN, NN, NN, 1.f);
  }
}

// Round 6
// 523.914 us; speedup vs baseline: 1.5262x; 1.0371x over previous
//
#include <hip/hip_runtime.h>
#include <stdint.h>

typedef short  short8  __attribute__((ext_vector_type(8)));
typedef unsigned short ushort8 __attribute__((ext_vector_type(8)));
typedef float  f32x4   __attribute__((ext_vector_type(4)));

#define BB  4
#define SQL 2048
#define SKL 2048
#define NEGV -1e9f
#define AS1 __attribute__((address_space(1)))
#define AS3 __attribute__((address_space(3)))

__device__ __forceinline__ unsigned short f2bf(float f){
  union { float f; uint32_t u; } x; x.f = f;
  return (unsigned short)((x.u + 0x7FFFu + ((x.u >> 16) & 1u)) >> 16);
}
__device__ __forceinline__ float bf2f(unsigned short h){
  union { uint32_t u; float f; } x; x.u = ((uint32_t)h) << 16;
  return x.f;
}

#define BARR() __builtin_amdgcn_s_barrier()
#define LGKM0() { asm volatile("s_waitcnt lgkmcnt(0)" ::: "memory"); __builtin_amdgcn_sched_barrier(0); }
#define VMW(N)  { asm volatile("s_waitcnt vmcnt(" #N ")" ::: "memory"); __builtin_amdgcn_sched_barrier(0); }
#define PRIO1 __builtin_amdgcn_s_setprio(1)
#define PRIO0 __builtin_amdgcn_s_setprio(0)

// ---------------- mask dtype sniffing ----------------
__global__ void mask_detect(const uint8_t* __restrict__ m, int* __restrict__ cnt){
  const long n4 = (long)BB * SQL * SKL / 4;
  long idx  = (long)blockIdx.x * blockDim.x + threadIdx.x;
  long step = (long)gridDim.x * blockDim.x;
  int c0 = 0, c1 = 0, c2 = 0;
  for (long i4 = idx; i4 < n4; i4 += step){
    uchar4 b = ((const uchar4*)m)[i4];
    c0 += (b.y != 0) + (b.z != 0) + (b.w != 0);
    c1 += (b.x > 1) + (b.y > 1) + (b.z > 1) + (b.w > 1);
    c2 += (b.y != 0);
  }
  #pragma unroll
  for (int o = 32; o >= 1; o >>= 1){
    c0 += __shfl_xor(c0, o); c1 += __shfl_xor(c1, o); c2 += __shfl_xor(c2, o);
  }
  if ((threadIdx.x & 63) == 0){
    atomicAdd(&cnt[0], c0); atomicAdd(&cnt[1], c1); atomicAdd(&cnt[2], c2);
  }
}

// ---------------- fused f32 -> bf16 conversion (6 tensors) ----------------
__global__ __launch_bounds__(256)
void cvt6(const float* __restrict__ s0, const float* __restrict__ s1,
          const float* __restrict__ s2, const float* __restrict__ s3,
          const float* __restrict__ s4, const float* __restrict__ s5,
          unsigned short* __restrict__ d0, unsigned short* __restrict__ d1,
          unsigned short* __restrict__ d2, unsigned short* __restrict__ d3,
          unsigned short* __restrict__ d4, unsigned short* __restrict__ d5)
{
  const long total = 7864320;  // 3*2097152 + 3*524288
  for (long c = (long)blockIdx.x * blockDim.x + threadIdx.x; c < total;
       c += (long)gridDim.x * blockDim.x){
    const float* s; unsigned short* d; long off;
    if      (c < 2097152){ s = s0; d = d0; off = c; }
    else if (c < 4194304){ s = s1; d = d1; off = c - 2097152; }
    else if (c < 6291456){ s = s2; d = d2; off = c - 4194304; }
    else if (c < 6815744){ s = s3; d = d3; off = c - 6291456; }
    else if (c < 7340032){ s = s4; d = d4; off = c - 6815744; }
    else                 { s = s5; d = d5; off = c - 7340032; }
    f32x4 a = ((const f32x4*)s)[off * 2];
    f32x4 b = ((const f32x4*)s)[off * 2 + 1];
    ushort8 w;
    #pragma unroll
    for (int j = 0; j < 4; ++j){ w[j] = f2bf(a[j]); w[j + 4] = f2bf(b[j]); }
    ((ushort8*)d)[off] = w;
  }
}

// ====== 256x256 NT GEMM, 4-phase/K-tile counted-vmcnt schedule (T3+T4) ======
// BM=BN=256, BK=64, 8 waves (wm=wid>>2 in {0,1}, wn=wid&3 in {0..3}), 128KiB LDS.
// Wave coverage interleaved across halves: rows {qm*128+wm*64+..}, cols
// {qn*128+wn*32+..} so each phase (qm,qn) touches exactly one A-half/B-half
// for ALL waves. Stage order t+1: {A0,B0,B1,A1}; quadrant order (0,0),(0,1),
// (1,1),(1,0); aF held across ph1-2 / ph3-4, bF[2] sets held whole tile.
// Waits (before phase-ending barrier -> collective): ph1:vmcnt(4) [own B1],
// ph2:vmcnt(4) [A1], ph4:vmcnt(4) [next A0,B0]. Never drain-0 in main loop.
template<int EPI>
__device__ __forceinline__ void gemm256_body(
    const unsigned short* __restrict__ Ag, const unsigned short* __restrict__ Bg,
    void* __restrict__ Cb, const void* __restrict__ mask, const int* __restrict__ cnt,
    int bz, long Cbs, long tm, long tn, float scale,
    unsigned short (&lA)[2][16384], unsigned short (&lB)[2][16384])
{
  constexpr int LD = 2048;
  const int tid = threadIdx.x, lane = tid & 63, wid = tid >> 6;
  const int wm = wid >> 2, wn = wid & 3;
  const int l15 = lane & 15, l16 = lane >> 4;

  f32x4 acc[2][2][4][2] = {};   // [qm][qn][mr][nr]
  short8 aF[4][2];              // current qm-half A frags [mr][ks]
  short8 bF[2][2][2];           // [qn][nr][ks], both halves live

  // stage one 128-row half (2 x global_load_lds 16B/thread, inverse-swizzled src)
  auto stageA = [&](int buf, int half, int k){
    const unsigned short* s = Ag + (tm + half * 128) * LD + k;
    unsigned short* d = lA[buf] + half * 8192;
    #pragma unroll
    for (int l = 0; l < 2; ++l){
      const int idx = l * 512 + tid;
      const int r   = idx >> 3;
      const int gsw = (idx & 7) ^ (r & 7);
      __builtin_amdgcn_global_load_lds((const AS1 void*)(s + r * LD + gsw * 8),
                                       (AS3 void*)(d + idx * 8), 16, 0, 0);
    }
  };
  auto stageB = [&](int buf, int half, int k){
    const unsigned short* s = Bg + (tn + half * 128) * LD + k;
    unsigned short* d = lB[buf] + half * 8192;
    #pragma unroll
    for (int l = 0; l < 2; ++l){
      const int idx = l * 512 + tid;
      const int r   = idx >> 3;
      const int gsw = (idx & 7) ^ (r & 7);
      __builtin_amdgcn_global_load_lds((const AS1 void*)(s + r * LD + gsw * 8),
                                       (AS3 void*)(d + idx * 8), 16, 0, 0);
    }
  };

  #define RD_A(BUF, QM)                                                       \
    _Pragma("unroll")                                                         \
    for (int mr = 0; mr < 4; ++mr)                                            \
      _Pragma("unroll")                                                       \
      for (int ks = 0; ks < 2; ++ks){                                         \
        const int r = (QM) * 128 + wm * 64 + mr * 16 + l15;                   \
        const int g = ks * 4 + l16;                                           \
        aF[mr][ks] = *(const short8*)&lA[BUF][(r * 8 + (g ^ (r & 7))) * 8];   \
      }
  #define RD_B(BUF, QN)                                                       \
    _Pragma("unroll")                                                         \
    for (int nr = 0; nr < 2; ++nr)                                            \
      _Pragma("unroll")                                                       \
      for (int ks = 0; ks < 2; ++ks){                                         \
        const int c = (QN) * 128 + wn * 32 + nr * 16 + l15;                   \
        const int g = ks * 4 + l16;                                           \
        bF[QN][nr][ks] = *(const short8*)&lB[BUF][(c * 8 + (g ^ (c & 7))) * 8]; \
      }
  #define MFMA16(QM, QN)                                                      \
    _Pragma("unroll")                                                         \
    for (int mr = 0; mr < 4; ++mr)                                            \
      _Pragma("unroll")                                                       \
      for (int nr = 0; nr < 2; ++nr)                                          \
        _Pragma("unroll")                                                     \
        for (int ks = 0; ks < 2; ++ks)                                        \
          acc[QM][QN][mr][nr] = __builtin_amdgcn_mfma_f32_16x16x32_bf16(      \
              aF[mr][ks], bF[QN][nr][ks], acc[QM][QN][mr][nr], 0, 0, 0);

  // steady-state K-tile: reads buf BUF, stages t+1 into BUF^1 at K-offset KNXT
  #define KTILE_MAIN(BUF, KNXT)                                               \
  {                                                                           \
    RD_A(BUF, 0); RD_B(BUF, 0);                                               \
    stageA((BUF) ^ 1, 0, (KNXT));                                             \
    BARR(); LGKM0();                                                          \
    PRIO1; MFMA16(0, 0); PRIO0; VMW(4); BARR();                               \
    RD_B(BUF, 1);                                                             \
    stageB((BUF) ^ 1, 0, (KNXT));                                             \
    BARR(); LGKM0();                                                          \
    PRIO1; MFMA16(0, 1); PRIO0; VMW(4); BARR();                               \
    RD_A(BUF, 1);                                                             \
    stageB((BUF) ^ 1, 1, (KNXT));                                             \
    BARR(); LGKM0();                                                          \
    PRIO1; MFMA16(1, 1); PRIO0; BARR();                                       \
    stageA((BUF) ^ 1, 1, (KNXT));                                             \
    BARR();                                                                   \
    PRIO1; MFMA16(1, 0); PRIO0; VMW(4); BARR();                               \
  }
  // final K-tile: no staging; drain progressively (once)
  #define KTILE_LAST(BUF)                                                     \
  {                                                                           \
    RD_A(BUF, 0); RD_B(BUF, 0);                                               \
    BARR(); LGKM0();                                                          \
    PRIO1; MFMA16(0, 0); PRIO0; VMW(2); BARR();                               \
    RD_B(BUF, 1);                                                             \
    BARR(); LGKM0();                                                          \
    PRIO1; MFMA16(0, 1); PRIO0; VMW(0); BARR();                               \
    RD_A(BUF, 1);                                                             \
    BARR(); LGKM0();                                                          \
    PRIO1; MFMA16(1, 1); PRIO0; BARR();                                       \
    PRIO1; MFMA16(1, 0); PRIO0;                                               \
  }

  // prologue: stage tile 0 {A0,B0,B1,A1}; wait A0,B0 (oldest 4)
  stageA(0, 0, 0);
  stageB(0, 0, 0);
  stageB(0, 1, 0);
  stageA(0, 1, 0);
  VMW(4); BARR();

  for (int it = 0; it < 15; ++it){
    KTILE_MAIN(0, (2 * it + 1) * 64);
    KTILE_MAIN(1, (2 * it + 2) * 64);
  }
  KTILE_MAIN(0, 31 * 64);
  KTILE_LAST(1);

  // ---- epilogue ---- C/D layout: col = lane&15, row = (lane>>4)*4 + j
  const int colo = l15, rowg = l16 * 4;
  if constexpr (EPI == 0){
    unsigned short* C = (unsigned short*)Cb + (long)bz * Cbs;
    #pragma unroll
    for (int qm = 0; qm < 2; ++qm)
      #pragma unroll
      for (int qn = 0; qn < 2; ++qn)
        #pragma unroll
        for (int mr = 0; mr < 4; ++mr)
          #pragma unroll
          for (int j = 0; j < 4; ++j){
            const long row = tm + qm * 128 + wm * 64 + mr * 16 + rowg + j;
            unsigned short* cr = C + row * LD + tn + qn * 128 + wn * 32 + colo;
            #pragma unroll
            for (int nr = 0; nr < 2; ++nr) cr[nr * 16] = f2bf(acc[qm][qn][mr][nr][j]);
          }
  } else if constexpr (EPI == 2){
    float* C = (float*)Cb + (long)bz * Cbs;
    #pragma unroll
    for (int qm = 0; qm < 2; ++qm)
      #pragma unroll
      for (int qn = 0; qn < 2; ++qn)
        #pragma unroll
        for (int mr = 0; mr < 4; ++mr)
          #pragma unroll
          for (int j = 0; j < 4; ++j){
            const long row = tm + qm * 128 + wm * 64 + mr * 16 + rowg + j;
            float* cr = C + row * LD + tn + qn * 128 + wn * 32 + colo;
            #pragma unroll
            for (int nr = 0; nr < 2; ++nr) cr[nr * 16] = acc[qm][qn][mr][nr][j];
          }
  } else {
    const int a0 = cnt[0], a1 = cnt[1], a2 = cnt[2];
    const int mmode = (a1 == 0) ? (a0 > 1000 ? 0 : 1) : (a2 > 1000 ? 2 : 3);
    unsigned short* C = (unsigned short*)Cb + (long)bz * Cbs;
    const long mbase = (long)bz * SQL * SKL;
    #pragma unroll
    for (int qm = 0; qm < 2; ++qm)
      #pragma unroll
      for (int qn = 0; qn < 2; ++qn)
        #pragma unroll
        for (int mr = 0; mr < 4; ++mr)
          #pragma unroll
          for (int j = 0; j < 4; ++j){
            const long row = tm + qm * 128 + wm * 64 + mr * 16 + rowg + j;
            #pragma unroll
            for (int nr = 0; nr < 2; ++nr){
              const long col = tn + qn * 128 + wn * 32 + nr * 16 + colo;
              const long midx = mbase + row * SKL + col;
              bool msk;
              if (mmode == 0)      msk = ((const uint8_t*)mask)[midx] != 0;
              else if (mmode == 1) msk = ((const int*)mask)[midx] != 0;
              else if (mmode == 2) msk = ((const unsigned short*)mask)[midx] != 0;
              else                 msk = ((const uint32_t*)mask)[midx] != 0;
              float vv = acc[qm][qn][mr][nr][j] * scale;
              if (msk) vv = NEGV;
              C[row * SKL + col] = f2bf(vv);
            }
          }
  }
  #undef RD_A
  #undef RD_B
  #undef MFMA16
  #undef KTILE_MAIN
  #undef KTILE_LAST
}

// bijective XCD swizzle (nwg % 8 == 0 for all our grids)
__device__ __forceinline__ void xcd_decode(int& bx, int& by, int& bz){
  const int gx = gridDim.x, gy = gridDim.y;
  const int nwg = gx * gy * gridDim.z;
  const int lid = blockIdx.x + gx * (blockIdx.y + gy * blockIdx.z);
  const int sw  = (lid & 7) * (nwg >> 3) + (lid >> 3);
  bx = sw % gx;
  const int t = sw / gx;
  by = t % gy;
  bz = t / gy;
}

template<int EPI>
__global__ __launch_bounds__(512, 2)
void gemm256(const unsigned short* __restrict__ A, const unsigned short* __restrict__ B,
             void* __restrict__ Cb, const void* __restrict__ mask,
             const int* __restrict__ cnt, long Abs, long Bbs, long Cbs, float scale)
{
  __shared__ unsigned short lA[2][16384];
  __shared__ unsigned short lB[2][16384];
  int bx, by, bz; xcd_decode(bx, by, bz);
  gemm256_body<EPI>(A + (long)bz * Abs, B + (long)bz * Bbs, Cb, mask, cnt, bz, Cbs,
                    (long)by * 256, (long)bx * 256, scale, lA, lB);
}

// three projections fused, 256^2 tiles: z 0-3 -> Q, 4-7 -> K', 8-11 -> V^T
__global__ __launch_bounds__(512, 2)
void gemm256_proj3(const unsigned short* A0, const unsigned short* A1, const unsigned short* A2,
                   const unsigned short* B0, const unsigned short* B1, const unsigned short* B2,
                   void* C0, void* C1, void* C2)
{
  __shared__ unsigned short lA[2][16384];
  __shared__ unsigned short lB[2][16384];
  int bx, by, bz; xcd_decode(bx, by, bz);
  const int sec = bz >> 2, b = bz & 3;
  const long NN = (long)SQL * 2048;
  const unsigned short* Av = sec == 0 ? A0 : sec == 1 ? A1 : A2;
  const unsigned short* Bv = sec == 0 ? B0 : sec == 1 ? B1 : B2;
  void*                 Cv = sec == 0 ? C0 : sec == 1 ? C1 : C2;
  const long Abs = (sec == 2) ? 0 : NN;
  const long Bbs = (sec == 2) ? NN : 0;
  gemm256_body<0>(Av + (long)b * Abs, Bv + (long)b * Bbs, Cv, nullptr, nullptr, b, NN,
                  (long)by * 256, (long)bx * 256, 1.f, lA, lB);
}

// ============ fallback 128x128 4-wave GEMM (round-4, proven) ============
template<int AMODE, int BMODE, int EPI>
__device__ __forceinline__ void gemm_body(
    const void* __restrict__ Av, const void* __restrict__ Bv,
    void* __restrict__ Cb, const void* __restrict__ mask, const int* __restrict__ cnt,
    int bz, long Abs, long Bbs, long Cbs, long tm, long tn, float scale,
    unsigned short (*lA)[4096], unsigned short (*lB)[4096])
{
  constexpr int K = 2048, LD = 2048;
  const int tid = threadIdx.x, lane = tid & 63, wave = tid >> 6;
  const int wr = wave >> 1, wc = wave & 1;
  const int c0 = tid, c1 = tid + 256;
  const int r0 = c0 >> 2, q0 = (c0 & 3) * 8;
  const int r1 = c1 >> 2, q1 = (c1 & 3) * 8;

  const unsigned short* A16 = (const unsigned short*)Av + (long)bz * Abs;
  const unsigned short* B16 = (const unsigned short*)Bv + (long)bz * Bbs;
  const float*          A32 = (const float*)Av + (long)bz * Abs;
  const float*          B32 = (const float*)Bv + (long)bz * Bbs;

  f32x4 acc[4][4] = {};
  f32x4 sA[4], sB[4];

  auto issueA = [&](int buf, int kk){
    if constexpr (AMODE == 0){
      __builtin_amdgcn_global_load_lds((const AS1 void*)(A16 + (tm + r0) * LD + q0 + kk),
                                       (AS3 void*)(lA[buf] + c0 * 8), 16, 0, 0);
      __builtin_amdgcn_global_load_lds((const AS1 void*)(A16 + (tm + r1) * LD + q1 + kk),
                                       (AS3 void*)(lA[buf] + c1 * 8), 16, 0, 0);
    } else {
      sA[0] = *(const f32x4*)(A32 + (tm + r0) * LD + q0 + kk);
      sA[1] = *(const f32x4*)(A32 + (tm + r0) * LD + q0 + kk + 4);
      sA[2] = *(const f32x4*)(A32 + (tm + r1) * LD + q1 + kk);
      sA[3] = *(const f32x4*)(A32 + (tm + r1) * LD + q1 + kk + 4);
    }
  };
  auto issueB = [&](int buf, int kk){
    if constexpr (BMODE == 0){
      __builtin_amdgcn_global_load_lds((const AS1 void*)(B16 + (tn + r0) * LD + q0 + kk),
                                       (AS3 void*)(lB[buf] + c0 * 8), 16, 0, 0);
      __builtin_amdgcn_global_load_lds((const AS1 void*)(B16 + (tn + r1) * LD + q1 + kk),
                                       (AS3 void*)(lB[buf] + c1 * 8), 16, 0, 0);
    } else {
      sB[0] = *(const f32x4*)(B32 + (tn + r0) * LD + q0 + kk);
      sB[1] = *(const f32x4*)(B32 + (tn + r0) * LD + q0 + kk + 4);
      sB[2] = *(const f32x4*)(B32 + (tn + r1) * LD + q1 + kk);
      sB[3] = *(const f32x4*)(B32 + (tn + r1) * LD + q1 + kk + 4);
    }
  };
  auto writeA = [&](int buf){
    if constexpr (AMODE == 1){
      ushort8 w0, w1;
      #pragma unroll
      for (int j = 0; j < 4; ++j){
        w0[j] = f2bf(sA[0][j]); w0[j + 4] = f2bf(sA[1][j]);
        w1[j] = f2bf(sA[2][j]); w1[j + 4] = f2bf(sA[3][j]);
      }
      *(ushort8*)(lA[buf] + c0 * 8) = w0;
      *(ushort8*)(lA[buf] + c1 * 8) = w1;
    }
  };
  auto writeB = [&](int buf){
    if constexpr (BMODE == 1){
      ushort8 w0, w1;
      #pragma unroll
      for (int j = 0; j < 4; ++j){
        w0[j] = f2bf(sB[0][j]); w0[j + 4] = f2bf(sB[1][j]);
        w1[j] = f2bf(sB[2][j]); w1[j + 4] = f2bf(sB[3][j]);
      }
      *(ushort8*)(lB[buf] + c0 * 8) = w0;
      *(ushort8*)(lB[buf] + c1 * 8) = w1;
    }
  };
  auto computeTile = [&](int buf){
    short8 aF[4], bF[4];
    #pragma unroll
    for (int m = 0; m < 4; ++m)
      aF[m] = *(const short8*)(lA[buf] + (wr * 64 + m * 16 + (lane & 15)) * 32 + (lane >> 4) * 8);
    #pragma unroll
    for (int n = 0; n < 4; ++n)
      bF[n] = *(const short8*)(lB[buf] + (wc * 64 + n * 16 + (lane & 15)) * 32 + (lane >> 4) * 8);
    #pragma unroll
    for (int m = 0; m < 4; ++m)
      #pragma unroll
      for (int n = 0; n < 4; ++n)
        acc[m][n] = __builtin_amdgcn_mfma_f32_16x16x32_bf16(aF[m], bF[n], acc[m][n], 0, 0, 0);
  };

  issueA(0, 0); issueB(0, 0); writeA(0); writeB(0);
  __syncthreads();
  int cur = 0;
  for (int k0 = 0; k0 < K - 32; k0 += 32){
    issueA(cur ^ 1, k0 + 32);
    issueB(cur ^ 1, k0 + 32);
    computeTile(cur);
    writeA(cur ^ 1); writeB(cur ^ 1);
    __syncthreads();
    cur ^= 1;
  }
  computeTile(cur);

  const int colo = lane & 15, rowg = (lane >> 4) * 4;
  if constexpr (EPI == 0){
    unsigned short* C = (unsigned short*)Cb + (long)bz * Cbs;
    #pragma unroll
    for (int m = 0; m < 4; ++m)
      #pragma unroll
      for (int j = 0; j < 4; ++j){
        const long row = tm + wr * 64 + m * 16 + rowg + j;
        unsigned short* cr = C + row * LD + tn + wc * 64 + colo;
        #pragma unroll
        for (int n = 0; n < 4; ++n) cr[n * 16] = f2bf(acc[m][n][j]);
      }
  } else if constexpr (EPI == 2){
    float* C = (float*)Cb + (long)bz * Cbs;
    #pragma unroll
    for (int m = 0; m < 4; ++m)
      #pragma unroll
      for (int j = 0; j < 4; ++j){
        const long row = tm + wr * 64 + m * 16 + rowg + j;
        float* cr = C + row * LD + tn + wc * 64 + colo;
        #pragma unroll
        for (int n = 0; n < 4; ++n) cr[n * 16] = acc[m][n][j];
      }
  } else {
    const int a0 = cnt[0], a1 = cnt[1], a2 = cnt[2];
    const int mmode = (a1 == 0) ? (a0 > 1000 ? 0 : 1) : (a2 > 1000 ? 2 : 3);
    unsigned short* C = (unsigned short*)Cb + (long)bz * Cbs;
    const long mbase = (long)bz * SQL * SKL;
    #pragma unroll
    for (int m = 0; m < 4; ++m)
      #pragma unroll
      for (int j = 0; j < 4; ++j){
        const long row = tm + wr * 64 + m * 16 + rowg + j;
        #pragma unroll
        for (int n = 0; n < 4; ++n){
          const long col = tn + wc * 64 + n * 16 + colo;
          const long midx = mbase + row * SKL + col;
          bool msk;
          if (mmode == 0)      msk = ((const uint8_t*)mask)[midx] != 0;
          else if (mmode == 1) msk = ((const int*)mask)[midx] != 0;
          else if (mmode == 2) msk = ((const unsigned short*)mask)[midx] != 0;
          else                 msk = ((const uint32_t*)mask)[midx] != 0;
          float vv = acc[m][n][j] * scale;
          if (msk) vv = NEGV;
          C[row * SKL + col] = f2bf(vv);
        }
      }
  }
}

template<int AMODE, int BMODE, int EPI>
__global__ __launch_bounds__(256, 2)
void gemm_nt(const void* __restrict__ Abv, const void* __restrict__ Bbv,
             void* __restrict__ Cb, const void* __restrict__ mask,
             const int* __restrict__ cnt,
             long Abs, long Bbs, long Cbs, float scale)
{
  __shared__ unsigned short lA[2][4096];
  __shared__ unsigned short lB[2][4096];
  int bx, by, bz; xcd_decode(bx, by, bz);
  gemm_body<AMODE, BMODE, EPI>(Abv, Bbv, Cb, mask, cnt, bz, Abs, Bbs, Cbs,
                               (long)by * 128, (long)bx * 128, scale, lA, lB);
}

template<int MODE>
__global__ __launch_bounds__(256, 2)
void gemm_proj3(const void* A0, const void* A1, const void* A2,
                const void* B0, const void* B1, const void* B2,
                void* C0, void* C1, void* C2)
{
  __shared__ unsigned short lA[2][4096];
  __shared__ unsigned short lB[2][4096];
  int bx, by, bz; xcd_decode(bx, by, bz);
  const int sec = bz >> 2, b = bz & 3;
  const long NN = (long)SQL * 2048;
  const void* Av = sec == 0 ? A0 : sec == 1 ? A1 : A2;
  const void* Bv = sec == 0 ? B0 : sec == 1 ? B1 : B2;
  void*       Cv = sec == 0 ? C0 : sec == 1 ? C1 : C2;
  const long Abs = (sec == 2) ? 0 : NN;
  const long Bbs = (sec == 2) ? NN : 0;
  gemm_body<MODE, MODE, 0>(Av, Bv, Cv, nullptr, nullptr, b, Abs, Bbs, NN,
                           (long)by * 128, (long)bx * 128, 1.f, lA, lB);
}

// ---------------- row softmax: S bf16 [row,0..2047] -> P bf16 ----------------
__global__ __launch_bounds__(256, 4)
void softmax_rows(const unsigned short* __restrict__ S, unsigned short* __restrict__ P){
  const long row = blockIdx.x;
  const int t = threadIdx.x;
  ushort8 u = *((const ushort8*)(S + row * SKL) + t);
  float v[8];
  #pragma unroll
  for (int j = 0; j < 8; ++j) v[j] = bf2f(u[j]);
  float mx = v[0];
  #pragma unroll
  for (int j = 1; j < 8; ++j) mx = fmaxf(mx, v[j]);
  #pragma unroll
  for (int o = 32; o >= 1; o >>= 1) mx = fmaxf(mx, __shfl_xor(mx, o));
  __shared__ float red[8];
  const int wv = t >> 6, ln = t & 63;
  if (ln == 0) red[wv] = mx;
  __syncthreads();
  mx = fmaxf(fmaxf(red[0], red[1]), fmaxf(red[2], red[3]));
  float e[8], sum = 0.f;
  #pragma unroll
  for (int j = 0; j < 8; ++j){ e[j] = exp2f((v[j] - mx) * 1.4426950408889634f); sum += e[j]; }
  #pragma unroll
  for (int o = 32; o >= 1; o >>= 1) sum += __shfl_xor(sum, o);
  if (ln == 0) red[4 + wv] = sum;
  __syncthreads();
  sum = red[4] + red[5] + red[6] + red[7];
  const float inv = 1.0f / sum;
  ushort8 o8;
  #pragma unroll
  for (int j = 0; j < 8; ++j) o8[j] = f2bf(e[j] * inv);
  *((ushort8*)(P + row * SKL) + t) = o8;
}

// ---------------- host ----------------
extern "C" void kernel_launch(void* const* d_in, const int* in_sizes, int n_in,
                              void* d_out, int out_size, void* d_ws, size_t ws_size,
                              hipStream_t stream)
{
  (void)in_sizes; (void)n_in; (void)out_size;
  const void* x    = d_in[0];
  const void* encq = d_in[1];
  const void* enck = d_in[2];
  const void* imsk = d_in[3];
  const void* Wq   = d_in[4];
  const void* Wk   = d_in[5];
  const void* Wv   = d_in[6];

  uint8_t* ws = (uint8_t*)d_ws;
  int* cnt = (int*)ws;
  const long NN = (long)2048 * 2048;
  const float scale = 0.022097086912079608f;  // 1/sqrt(2048)

  hipMemsetAsync(cnt, 0, 4096, stream);
  mask_detect<<<256, 256, 0, stream>>>((const uint8_t*)imsk, cnt);

  const size_t ENC = 33554432, WSZ = 8388608;
  const size_t FULL_NEED = 4096 + 3 * ENC + 3 * WSZ + 2 * ENC;
  if (ws_size >= FULL_NEED){
    unsigned short* xb  = (unsigned short*)(ws + 4096);
    unsigned short* qb  = xb + 16777216;
    unsigned short* kb  = qb + 16777216;
    unsigned short* Wqb = kb + 16777216;
    unsigned short* Wkb = Wqb + 4194304;
    unsigned short* Wvb = Wkb + 4194304;
    unsigned short* Kp  = Wvb + 4194304;
    unsigned short* Vt  = Kp + 16777216;
    unsigned short* Q   = (unsigned short*)d_out;         // [0, 32MiB)
    unsigned short* S   = Q + 16777216;                   // [32MiB, 64MiB)
    unsigned short* P   = qb;                             // qb dead after Q-proj

    cvt6<<<2048, 256, 0, stream>>>((const float*)x, (const float*)encq, (const float*)enck,
                                   (const float*)Wq, (const float*)Wk, (const float*)Wv,
                                   xb, qb, kb, Wqb, Wkb, Wvb);
    gemm256_proj3<<<dim3(8, 8, 12), 512, 0, stream>>>(qb, kb, Wvb, Wqb, Wkb, xb, Q, Kp, Vt);
    gemm256<1><<<dim3(8, 8, BB), 512, 0, stream>>>(Q, Kp, S, imsk, cnt, NN, NN, NN, scale);
    softmax_rows<<<BB * SQL, 256, 0, stream>>>(S, P);
    gemm256<2><<<dim3(8, 8, BB), 512, 0, stream>>>(P, Vt, d_out, nullptr, cnt, NN, NN, NN, 1.f);
  } else {
    unsigned short* Q  = (unsigned short*)(ws + 4096);
    unsigned short* Kp = Q  + 16777216;
    unsigned short* Vt = Kp + 16777216;
    unsigned short* P  = Q;
    unsigned short* S;
    const size_t need = 4096 + 4ull * 33554432;
    if (ws_size >= need) S = Vt + 16777216;
    else                 S = (unsigned short*)d_out;

    gemm_proj3<1><<<dim3(16, 16, 12), 256, 0, stream>>>(encq, enck, Wv, Wq, Wk, x, Q, Kp, Vt);
    gemm_nt<0, 0, 1><<<dim3(16, 16, BB), 256, 0, stream>>>(Q, Kp, S, imsk, cnt, NN, NN, NN, scale);
    softmax_rows<<<BB * SQL, 256, 0, stream>>>(S, P);
    gemm_nt<0, 0, 2><<<dim3(16, 16, BB), 256, 0, stream>>>(P, Vt, d_out, nullptr, cnt, NN, NN, NN, 1.f);
  }
}